// Round 3
// baseline (4034.096 us; speedup 1.0000x reference)
//
#include <hip/hip_runtime.h>

typedef unsigned short u16;
typedef unsigned int u32;

#define N_NODES 64000
#define DIM 64
#define NGRAPH 320
#define NPG 200
#define NEDGE 1024000
#define EPG 3200
#define NSTEPS 5
#define NITERS 6

__device__ __forceinline__ float bf2f(u16 u) {
  u32 x = ((u32)u) << 16;
  float f;
  __builtin_memcpy(&f, &x, 4);
  return f;
}
__device__ __forceinline__ u16 f2bf(float f) {
  u32 x;
  __builtin_memcpy(&x, &f, 4);
  x = (x + 0x7FFFu + ((x >> 16) & 1u)) >> 16;
  return (u16)x;
}
__device__ __forceinline__ float sigmf(float x) { return 1.0f / (1.0f + __expf(-x)); }

// ---------------- prep kernels ----------------

__global__ void k_pack(const int* __restrict__ src, const int* __restrict__ dst,
                       const int* __restrict__ ety, u32* __restrict__ packed) {
  int e = blockIdx.x * 256 + threadIdx.x;
  if (e < NEDGE) {
    int g = e / EPG;
    int base = g * NPG;
    packed[e] = (u32)(src[e] - base) | ((u32)(dst[e] - base) << 8) | ((u32)ety[e] << 16);
  }
}

__global__ void k_transpose(const float* __restrict__ src, float* __restrict__ dst, int R, int C) {
  int i = blockIdx.x * 256 + threadIdx.x;
  if (i < R * C) {
    int r = i / C, c = i - r * C;
    dst[c * R + r] = src[i];
  }
}

// ---------------- per-step kernels ----------------

// Wh[t][n][o] = sum_d h[n][d] * W_edge[t][d][o] + b_edge[t][o], stored bf16
__global__ void __launch_bounds__(256) k_wh(const float* __restrict__ h,
                                            const float* __restrict__ W_edge,
                                            const float* __restrict__ b_edge,
                                            u16* __restrict__ Whb) {
  __shared__ __align__(16) float h_s[64 * 64];
  int tid = threadIdx.x;
  int o = tid & 63, nl = tid >> 6;
  int t = blockIdx.y;
  int n0 = blockIdx.x * 64;
  for (int i = tid; i < 4096; i += 256) h_s[i] = h[(size_t)n0 * 64 + i];
  float wcol[64];
#pragma unroll
  for (int k = 0; k < 64; k++) wcol[k] = W_edge[(t * 64 + k) * 64 + o];
  float bias = b_edge[t * 64 + o];
  __syncthreads();
  for (int ng = 0; ng < 16; ng++) {
    int n = ng * 4 + nl;
    float acc = bias;
#pragma unroll
    for (int k4 = 0; k4 < 16; k4++) {
      float4 hv = *(const float4*)&h_s[n * 64 + k4 * 4];
      acc += hv.x * wcol[k4 * 4] + hv.y * wcol[k4 * 4 + 1] +
             hv.z * wcol[k4 * 4 + 2] + hv.w * wcol[k4 * 4 + 3];
    }
    Whb[((size_t)t * N_NODES + n0 + n) * 64 + o] = f2bf(acc);
  }
}

// one block per graph (512 threads = 8 waves).
// v3: packed staged in LDS; gather batched 16-deep for MLP; LDS fp32 atomic accumulate.
__global__ void __launch_bounds__(512) k_scatter(const u16* __restrict__ Whb,
                                                 const u32* __restrict__ packed,
                                                 float* __restrict__ a) {
  __shared__ float acc[NPG * 64];   // 50 KB
  __shared__ u32 pk[EPG];           // 12.8 KB
  int g = blockIdx.x;
  int tid = threadIdx.x;
  int lane = tid & 63, wid = tid >> 6;
  for (int i = tid; i < NPG * 64; i += 512) acc[i] = 0.f;
  for (int i = tid; i < EPG; i += 512) pk[i] = packed[g * EPG + i];
  __syncthreads();
  size_t nodebase = (size_t)g * NPG;
  const u16* Wg = Whb + nodebase * 64 + lane;   // + t*N_NODES*64 + s*64
  const int EW = EPG / 8;  // 400 edges per wave
  int e0 = wid * EW;
#pragma unroll 1
  for (int b = 0; b < EW; b += 16) {
    u32 p[16];
    float v[16];
#pragma unroll
    for (int j = 0; j < 16; j++) p[j] = pk[e0 + b + j];
#pragma unroll
    for (int j = 0; j < 16; j++) {
      int s = p[j] & 255;
      int t = (p[j] >> 16) & 7;
      v[j] = bf2f(Wg[((size_t)t * N_NODES + s) * 64]);
    }
#pragma unroll
    for (int j = 0; j < 16; j++) {
      int dl = (p[j] >> 8) & 255;
      atomicAdd(&acc[dl * 64 + lane], v[j]);
    }
  }
  __syncthreads();
  float* ag = a + nodebase * 64;
  for (int i = tid; i < NPG * 64; i += 512) ag[i] = acc[i];
}

// GRU: gi = a@W_ih^T + b_ih; gh = h@W_hh^T + b_hh; gate math; h updated in place.
__global__ void __launch_bounds__(256) k_gru(const float* __restrict__ a,
                                             float* __restrict__ h,
                                             const float* __restrict__ wt_gru,
                                             const float* __restrict__ b_ih,
                                             const float* __restrict__ b_hh) {
  __shared__ __align__(16) float a_s[32 * 64];
  __shared__ __align__(16) float h_s[32 * 64];
  __shared__ float gsum[32 * 192];
  __shared__ float ghn[32 * 64];
  int tid = threadIdx.x;
  int nb = blockIdx.x * 32;
  for (int i = tid; i < 2048; i += 256) {
    a_s[i] = a[(size_t)nb * 64 + i];
    h_s[i] = h[(size_t)nb * 64 + i];
  }
  float wih[64], whh[64];
  float bi = 0.f, bh = 0.f;
  int j = tid;
  if (j < 192) {
    bi = b_ih[j];
    bh = b_hh[j];
#pragma unroll
    for (int k = 0; k < 64; k++) {
      wih[k] = wt_gru[k * 192 + j];
      whh[k] = wt_gru[12288 + k * 192 + j];
    }
  }
  __syncthreads();
  if (j < 192) {
    for (int n = 0; n < 32; n++) {
      float gi = bi, gh = bh;
#pragma unroll
      for (int k4 = 0; k4 < 16; k4++) {
        float4 av = *(const float4*)&a_s[n * 64 + k4 * 4];
        float4 hv = *(const float4*)&h_s[n * 64 + k4 * 4];
        gi += av.x * wih[k4 * 4] + av.y * wih[k4 * 4 + 1] + av.z * wih[k4 * 4 + 2] + av.w * wih[k4 * 4 + 3];
        gh += hv.x * whh[k4 * 4] + hv.y * whh[k4 * 4 + 1] + hv.z * whh[k4 * 4 + 2] + hv.w * whh[k4 * 4 + 3];
      }
      if (j < 128) {
        gsum[n * 192 + j] = gi + gh;
      } else {
        gsum[n * 192 + j] = gi;
        ghn[n * 64 + (j - 128)] = gh;
      }
    }
  }
  __syncthreads();
  int d = tid & 63, nl = tid >> 6;
  for (int q = 0; q < 8; q++) {
    int n = q * 4 + nl;
    float r = sigmf(gsum[n * 192 + d]);
    float z = sigmf(gsum[n * 192 + 64 + d]);
    float gg = tanhf(gsum[n * 192 + 128 + d] + r * ghn[n * 64 + d]);
    float hv = h_s[n * 64 + d];
    h[(size_t)(nb + n) * 64 + d] = (1.0f - z) * gg + z * hv;
  }
}

// ---------------- Set2Set: one block per graph, all 6 iterations internal ----------------

__global__ void __launch_bounds__(256) k_set2set(
    const float* __restrict__ feat,
    const float* __restrict__ WTih0, const float* __restrict__ WThh0,
    const float* __restrict__ WTih1, const float* __restrict__ WThh1,
    const float* __restrict__ WTih2, const float* __restrict__ WThh2,
    const float* __restrict__ b_ih0, const float* __restrict__ b_hh0,
    const float* __restrict__ b_ih1, const float* __restrict__ b_hh1,
    const float* __restrict__ b_ih2, const float* __restrict__ b_hh2,
    const float* __restrict__ Wp, const float* __restrict__ bp,
    float* __restrict__ out) {
  __shared__ __align__(16) float feat_s[NPG * 64];
  __shared__ float qstar[128];
  __shared__ float xbuf[128];
  __shared__ float hs_s[3][64];
  __shared__ float cs_s[3][64];
  __shared__ float gates[256];
  __shared__ float e_s[NPG];
  __shared__ float red[4][64];
  __shared__ float scal[2];
  int tid = threadIdx.x;
  int g = blockIdx.x;
  int lane = tid & 63, wid = tid >> 6;
  for (int i = tid; i < NPG * 64; i += 256) feat_s[i] = feat[(size_t)g * NPG * 64 + i];
  if (tid < 128) { qstar[tid] = 0.f; xbuf[tid] = 0.f; }
  if (tid < 64) {
    for (int l = 0; l < 3; l++) { hs_s[l][tid] = 0.f; cs_s[l][tid] = 0.f; }
  }
  __syncthreads();
  for (int it = 0; it < NITERS; it++) {
    {
      float gj = b_ih0[tid] + b_hh0[tid];
      for (int k = 0; k < 128; k++) gj += qstar[k] * WTih0[k * 256 + tid];
      for (int k = 0; k < 64; k++) gj += hs_s[0][k] * WThh0[k * 256 + tid];
      gates[tid] = gj;
    }
    __syncthreads();
    if (tid < 64) {
      float c = sigmf(gates[64 + tid]) * cs_s[0][tid] + sigmf(gates[tid]) * tanhf(gates[128 + tid]);
      float x = sigmf(gates[192 + tid]) * tanhf(c);
      cs_s[0][tid] = c; hs_s[0][tid] = x; xbuf[tid] = x;
    }
    __syncthreads();
    for (int l = 1; l < 3; l++) {
      const float* Wi = (l == 1) ? WTih1 : WTih2;
      const float* Wh = (l == 1) ? WThh1 : WThh2;
      const float* bi = (l == 1) ? b_ih1 : b_ih2;
      const float* bh = (l == 1) ? b_hh1 : b_hh2;
      float gj = bi[tid] + bh[tid];
      for (int k = 0; k < 64; k++)
        gj += xbuf[k] * Wi[k * 256 + tid] + hs_s[l][k] * Wh[k * 256 + tid];
      gates[tid] = gj;
      __syncthreads();
      if (tid < 64) {
        float c = sigmf(gates[64 + tid]) * cs_s[l][tid] + sigmf(gates[tid]) * tanhf(gates[128 + tid]);
        float x = sigmf(gates[192 + tid]) * tanhf(c);
        cs_s[l][tid] = c; hs_s[l][tid] = x; xbuf[tid] = x;
      }
      __syncthreads();
    }
    for (int n = wid; n < NPG; n += 4) {
      float v = feat_s[n * 64 + lane] * xbuf[lane];
      for (int off = 32; off > 0; off >>= 1) v += __shfl_down(v, off);
      if (lane == 0) e_s[n] = v;
    }
    __syncthreads();
    if (tid < 64) {
      float m = -1e30f;
      for (int n = lane; n < NPG; n += 64) m = fmaxf(m, e_s[n]);
      for (int off = 32; off > 0; off >>= 1) m = fmaxf(m, __shfl_down(m, off));
      m = __shfl(m, 0);
      float ssum = 0.f;
      for (int n = lane; n < NPG; n += 64) {
        float ex = __expf(e_s[n] - m);
        e_s[n] = ex;
        ssum += ex;
      }
      for (int off = 32; off > 0; off >>= 1) ssum += __shfl_down(ssum, off);
      if (lane == 0) scal[0] = ssum;
    }
    __syncthreads();
    float denom = scal[0];
    {
      float r = 0.f;
      for (int n = wid; n < NPG; n += 4) r += feat_s[n * 64 + lane] * e_s[n];
      red[wid][lane] = r;
    }
    __syncthreads();
    if (tid < 64) {
      float ro = (red[0][lane] + red[1][lane] + red[2][lane] + red[3][lane]) / denom;
      qstar[lane] = xbuf[lane];
      qstar[64 + lane] = ro;
    }
    __syncthreads();
  }
  if (tid < 3) {
    float s = bp[tid];
    for (int k = 0; k < 128; k++) s += qstar[k] * Wp[tid * 128 + k];
    out[g * 3 + tid] = s;
  }
}

// ---------------- host ----------------

extern "C" void kernel_launch(void* const* d_in, const int* in_sizes, int n_in,
                              void* d_out, int out_size, void* d_ws, size_t ws_size,
                              hipStream_t stream) {
  const float* feats  = (const float*)d_in[0];
  const float* W_edge = (const float*)d_in[1];
  const float* b_edge = (const float*)d_in[2];
  const float* gWih   = (const float*)d_in[3];
  const float* gWhh   = (const float*)d_in[4];
  const float* gbih   = (const float*)d_in[5];
  const float* gbhh   = (const float*)d_in[6];
  const float* lWi0   = (const float*)d_in[7];
  const float* lWh0   = (const float*)d_in[8];
  const float* lbi0   = (const float*)d_in[9];
  const float* lbh0   = (const float*)d_in[10];
  const float* lWi1   = (const float*)d_in[11];
  const float* lWh1   = (const float*)d_in[12];
  const float* lbi1   = (const float*)d_in[13];
  const float* lbh1   = (const float*)d_in[14];
  const float* lWi2   = (const float*)d_in[15];
  const float* lWh2   = (const float*)d_in[16];
  const float* lbi2   = (const float*)d_in[17];
  const float* lbh2   = (const float*)d_in[18];
  const float* Wp     = (const float*)d_in[19];
  const float* bp     = (const float*)d_in[20];
  const int* src      = (const int*)d_in[21];
  const int* dst      = (const int*)d_in[22];
  const int* ety      = (const int*)d_in[23];
  float* out = (float*)d_out;

  char* ws = (char*)d_ws;
  float* h      = (float*)ws;                    // 16,384,000 B
  float* a      = (float*)(ws + 16384000);       // 16,384,000 B
  u16*   Whb    = (u16*)(ws + 32768000);         // 49,152,000 B
  u32*   packed = (u32*)(ws + 81920000);         //  4,096,000 B
  float* wt_gru = (float*)(ws + 86016000);       //     98,304 B
  float* wtl    = (float*)(ws + 86114304);       //    458,752 B
  float* WTih0 = wtl;
  float* WThh0 = WTih0 + 32768;
  float* WTih1 = WThh0 + 16384;
  float* WThh1 = WTih1 + 16384;
  float* WTih2 = WThh1 + 16384;
  float* WThh2 = WTih2 + 16384;

  k_pack<<<NEDGE / 256, 256, 0, stream>>>(src, dst, ety, packed);
  k_transpose<<<48, 256, 0, stream>>>(gWih, wt_gru, 192, 64);
  k_transpose<<<48, 256, 0, stream>>>(gWhh, wt_gru + 12288, 192, 64);
  k_transpose<<<128, 256, 0, stream>>>(lWi0, WTih0, 256, 128);
  k_transpose<<<64, 256, 0, stream>>>(lWh0, WThh0, 256, 64);
  k_transpose<<<64, 256, 0, stream>>>(lWi1, WTih1, 256, 64);
  k_transpose<<<64, 256, 0, stream>>>(lWh1, WThh1, 256, 64);
  k_transpose<<<64, 256, 0, stream>>>(lWi2, WTih2, 256, 64);
  k_transpose<<<64, 256, 0, stream>>>(lWh2, WThh2, 256, 64);
  hipMemcpyAsync(h, feats, (size_t)N_NODES * DIM * sizeof(float),
                 hipMemcpyDeviceToDevice, stream);

  for (int s = 0; s < NSTEPS; s++) {
    k_wh<<<dim3(N_NODES / 64, 6), 256, 0, stream>>>(h, W_edge, b_edge, Whb);
    k_scatter<<<NGRAPH, 512, 0, stream>>>(Whb, packed, a);
    k_gru<<<N_NODES / 32, 256, 0, stream>>>(a, h, wt_gru, gbih, gbhh);
  }
  k_set2set<<<NGRAPH, 256, 0, stream>>>(h, WTih0, WThh0, WTih1, WThh1, WTih2, WThh2,
                                        lbi0, lbh0, lbi1, lbh1, lbi2, lbh2, Wp, bp, out);
}

// Round 4
// 3873.273 us; speedup vs baseline: 1.0415x; 1.0415x over previous
//
#include <hip/hip_runtime.h>

typedef unsigned short u16;
typedef unsigned int u32;

#define N_NODES 64000
#define DIM 64
#define NGRAPH 320
#define NPG 200
#define NEDGE 1024000
#define EPG 3200
#define NSTEPS 5
#define NITERS 6

__device__ __forceinline__ float bf2f(u16 u) {
  u32 x = ((u32)u) << 16;
  float f;
  __builtin_memcpy(&f, &x, 4);
  return f;
}
__device__ __forceinline__ u16 f2bf(float f) {
  u32 x;
  __builtin_memcpy(&x, &f, 4);
  x = (x + 0x7FFFu + ((x >> 16) & 1u)) >> 16;
  return (u16)x;
}
__device__ __forceinline__ float sigmf(float x) { return 1.0f / (1.0f + __expf(-x)); }

// ---------------- prep kernels ----------------

__global__ void k_pack(const int* __restrict__ src, const int* __restrict__ dst,
                       const int* __restrict__ ety, u32* __restrict__ packed) {
  int e = blockIdx.x * 256 + threadIdx.x;
  if (e < NEDGE) {
    int g = e / EPG;
    int base = g * NPG;
    packed[e] = (u32)(src[e] - base) | ((u32)(dst[e] - base) << 8) | ((u32)ety[e] << 16);
  }
}

__global__ void k_transpose(const float* __restrict__ src, float* __restrict__ dst, int R, int C) {
  int i = blockIdx.x * 256 + threadIdx.x;
  if (i < R * C) {
    int r = i / C, c = i - r * C;
    dst[c * R + r] = src[i];
  }
}

// ---------------- per-step kernels ----------------

// Wh[t][n][o] = sum_d h[n][d] * W_edge[t][d][o] + b_edge[t][o], stored bf16
__global__ void __launch_bounds__(256) k_wh(const float* __restrict__ h,
                                            const float* __restrict__ W_edge,
                                            const float* __restrict__ b_edge,
                                            u16* __restrict__ Whb) {
  __shared__ __align__(16) float h_s[64 * 64];
  int tid = threadIdx.x;
  int o = tid & 63, nl = tid >> 6;
  int t = blockIdx.y;
  int n0 = blockIdx.x * 64;
  for (int i = tid; i < 4096; i += 256) h_s[i] = h[(size_t)n0 * 64 + i];
  float wcol[64];
#pragma unroll
  for (int k = 0; k < 64; k++) wcol[k] = W_edge[(t * 64 + k) * 64 + o];
  float bias = b_edge[t * 64 + o];
  __syncthreads();
  for (int ng = 0; ng < 16; ng++) {
    int n = ng * 4 + nl;
    float acc = bias;
#pragma unroll
    for (int k4 = 0; k4 < 16; k4++) {
      float4 hv = *(const float4*)&h_s[n * 64 + k4 * 4];
      acc += hv.x * wcol[k4 * 4] + hv.y * wcol[k4 * 4 + 1] +
             hv.z * wcol[k4 * 4 + 2] + hv.w * wcol[k4 * 4 + 3];
    }
    Whb[((size_t)t * N_NODES + n0 + n) * 64 + o] = f2bf(acc);
  }
}

// v4: grid (NGRAPH, 2). Block (g, th) stages the 3-etype Whb slice for graph g
// into LDS (76.8KB), edges into LDS, accumulates in a 50KB LDS fp32 buffer with
// LDS atomics (all-LDS inner loop), then flushes via global atomicAdd into a
// (a pre-zeroed with hipMemsetAsync). All global traffic coalesced streaming.
__global__ void __launch_bounds__(512) k_scatter(const u16* __restrict__ Whb,
                                                 const u32* __restrict__ packed,
                                                 float* __restrict__ a) {
  __shared__ u16 wh_s[3 * NPG * 64];   // 76,800 B
  __shared__ float acc[NPG * 64];      // 51,200 B
  __shared__ u32 pk[EPG];              // 12,800 B
  int g = blockIdx.x;
  int t0 = blockIdx.y * 3;
  int tid = threadIdx.x;
  int lane = tid & 63, wid = tid >> 6;
  size_t nodebase = (size_t)g * NPG;
  // stage Whb slice for types t0..t0+2 (contiguous 25.6KB per type) as u32
  {
    u32* ws32 = (u32*)wh_s;
    for (int t = 0; t < 3; t++) {
      const u32* src32 = (const u32*)(Whb + ((size_t)(t0 + t) * N_NODES + nodebase) * 64);
      u32* dst32 = ws32 + t * (NPG * 32);
      for (int i = tid; i < NPG * 32; i += 512) dst32[i] = src32[i];
    }
  }
  for (int i = tid; i < NPG * 64; i += 512) acc[i] = 0.f;
  for (int i = tid; i < EPG; i += 512) pk[i] = packed[g * EPG + i];
  __syncthreads();
  const int EW = EPG / 8;  // 400 edges per wave
  int e0 = wid * EW;
#pragma unroll 4
  for (int i = 0; i < EW; i++) {
    u32 p = pk[e0 + i];
    u32 tt = (p >> 16) - (u32)t0;
    if (tt < 3u) {
      int s = p & 255;
      int dl = (p >> 8) & 255;
      float v = bf2f(wh_s[(tt * NPG + s) * 64 + lane]);
      atomicAdd(&acc[dl * 64 + lane], v);
    }
  }
  __syncthreads();
  float* ag = a + nodebase * 64;
  for (int i = tid; i < NPG * 64; i += 512) atomicAdd(&ag[i], acc[i]);
}

// GRU: gi = a@W_ih^T + b_ih; gh = h@W_hh^T + b_hh; gate math; h updated in place.
__global__ void __launch_bounds__(256) k_gru(const float* __restrict__ a,
                                             float* __restrict__ h,
                                             const float* __restrict__ wt_gru,
                                             const float* __restrict__ b_ih,
                                             const float* __restrict__ b_hh) {
  __shared__ __align__(16) float a_s[32 * 64];
  __shared__ __align__(16) float h_s[32 * 64];
  __shared__ float gsum[32 * 192];
  __shared__ float ghn[32 * 64];
  int tid = threadIdx.x;
  int nb = blockIdx.x * 32;
  for (int i = tid; i < 2048; i += 256) {
    a_s[i] = a[(size_t)nb * 64 + i];
    h_s[i] = h[(size_t)nb * 64 + i];
  }
  float wih[64], whh[64];
  float bi = 0.f, bh = 0.f;
  int j = tid;
  if (j < 192) {
    bi = b_ih[j];
    bh = b_hh[j];
#pragma unroll
    for (int k = 0; k < 64; k++) {
      wih[k] = wt_gru[k * 192 + j];
      whh[k] = wt_gru[12288 + k * 192 + j];
    }
  }
  __syncthreads();
  if (j < 192) {
    for (int n = 0; n < 32; n++) {
      float gi = bi, gh = bh;
#pragma unroll
      for (int k4 = 0; k4 < 16; k4++) {
        float4 av = *(const float4*)&a_s[n * 64 + k4 * 4];
        float4 hv = *(const float4*)&h_s[n * 64 + k4 * 4];
        gi += av.x * wih[k4 * 4] + av.y * wih[k4 * 4 + 1] + av.z * wih[k4 * 4 + 2] + av.w * wih[k4 * 4 + 3];
        gh += hv.x * whh[k4 * 4] + hv.y * whh[k4 * 4 + 1] + hv.z * whh[k4 * 4 + 2] + hv.w * whh[k4 * 4 + 3];
      }
      if (j < 128) {
        gsum[n * 192 + j] = gi + gh;
      } else {
        gsum[n * 192 + j] = gi;
        ghn[n * 64 + (j - 128)] = gh;
      }
    }
  }
  __syncthreads();
  int d = tid & 63, nl = tid >> 6;
  for (int q = 0; q < 8; q++) {
    int n = q * 4 + nl;
    float r = sigmf(gsum[n * 192 + d]);
    float z = sigmf(gsum[n * 192 + 64 + d]);
    float gg = tanhf(gsum[n * 192 + 128 + d] + r * ghn[n * 64 + d]);
    float hv = h_s[n * 64 + d];
    h[(size_t)(nb + n) * 64 + d] = (1.0f - z) * gg + z * hv;
  }
}

// ---------------- Set2Set: one block per graph, all 6 iterations internal ----------------

__global__ void __launch_bounds__(256) k_set2set(
    const float* __restrict__ feat,
    const float* __restrict__ WTih0, const float* __restrict__ WThh0,
    const float* __restrict__ WTih1, const float* __restrict__ WThh1,
    const float* __restrict__ WTih2, const float* __restrict__ WThh2,
    const float* __restrict__ b_ih0, const float* __restrict__ b_hh0,
    const float* __restrict__ b_ih1, const float* __restrict__ b_hh1,
    const float* __restrict__ b_ih2, const float* __restrict__ b_hh2,
    const float* __restrict__ Wp, const float* __restrict__ bp,
    float* __restrict__ out) {
  __shared__ __align__(16) float feat_s[NPG * 64];
  __shared__ float qstar[128];
  __shared__ float xbuf[128];
  __shared__ float hs_s[3][64];
  __shared__ float cs_s[3][64];
  __shared__ float gates[256];
  __shared__ float e_s[NPG];
  __shared__ float red[4][64];
  __shared__ float scal[2];
  int tid = threadIdx.x;
  int g = blockIdx.x;
  int lane = tid & 63, wid = tid >> 6;
  for (int i = tid; i < NPG * 64; i += 256) feat_s[i] = feat[(size_t)g * NPG * 64 + i];
  if (tid < 128) { qstar[tid] = 0.f; xbuf[tid] = 0.f; }
  if (tid < 64) {
    for (int l = 0; l < 3; l++) { hs_s[l][tid] = 0.f; cs_s[l][tid] = 0.f; }
  }
  __syncthreads();
  for (int it = 0; it < NITERS; it++) {
    {
      float gj = b_ih0[tid] + b_hh0[tid];
      for (int k = 0; k < 128; k++) gj += qstar[k] * WTih0[k * 256 + tid];
      for (int k = 0; k < 64; k++) gj += hs_s[0][k] * WThh0[k * 256 + tid];
      gates[tid] = gj;
    }
    __syncthreads();
    if (tid < 64) {
      float c = sigmf(gates[64 + tid]) * cs_s[0][tid] + sigmf(gates[tid]) * tanhf(gates[128 + tid]);
      float x = sigmf(gates[192 + tid]) * tanhf(c);
      cs_s[0][tid] = c; hs_s[0][tid] = x; xbuf[tid] = x;
    }
    __syncthreads();
    for (int l = 1; l < 3; l++) {
      const float* Wi = (l == 1) ? WTih1 : WTih2;
      const float* Wh = (l == 1) ? WThh1 : WThh2;
      const float* bi = (l == 1) ? b_ih1 : b_ih2;
      const float* bh = (l == 1) ? b_hh1 : b_hh2;
      float gj = bi[tid] + bh[tid];
      for (int k = 0; k < 64; k++)
        gj += xbuf[k] * Wi[k * 256 + tid] + hs_s[l][k] * Wh[k * 256 + tid];
      gates[tid] = gj;
      __syncthreads();
      if (tid < 64) {
        float c = sigmf(gates[64 + tid]) * cs_s[l][tid] + sigmf(gates[tid]) * tanhf(gates[128 + tid]);
        float x = sigmf(gates[192 + tid]) * tanhf(c);
        cs_s[l][tid] = c; hs_s[l][tid] = x; xbuf[tid] = x;
      }
      __syncthreads();
    }
    for (int n = wid; n < NPG; n += 4) {
      float v = feat_s[n * 64 + lane] * xbuf[lane];
      for (int off = 32; off > 0; off >>= 1) v += __shfl_down(v, off);
      if (lane == 0) e_s[n] = v;
    }
    __syncthreads();
    if (tid < 64) {
      float m = -1e30f;
      for (int n = lane; n < NPG; n += 64) m = fmaxf(m, e_s[n]);
      for (int off = 32; off > 0; off >>= 1) m = fmaxf(m, __shfl_down(m, off));
      m = __shfl(m, 0);
      float ssum = 0.f;
      for (int n = lane; n < NPG; n += 64) {
        float ex = __expf(e_s[n] - m);
        e_s[n] = ex;
        ssum += ex;
      }
      for (int off = 32; off > 0; off >>= 1) ssum += __shfl_down(ssum, off);
      if (lane == 0) scal[0] = ssum;
    }
    __syncthreads();
    float denom = scal[0];
    {
      float r = 0.f;
      for (int n = wid; n < NPG; n += 4) r += feat_s[n * 64 + lane] * e_s[n];
      red[wid][lane] = r;
    }
    __syncthreads();
    if (tid < 64) {
      float ro = (red[0][lane] + red[1][lane] + red[2][lane] + red[3][lane]) / denom;
      qstar[lane] = xbuf[lane];
      qstar[64 + lane] = ro;
    }
    __syncthreads();
  }
  if (tid < 3) {
    float s = bp[tid];
    for (int k = 0; k < 128; k++) s += qstar[k] * Wp[tid * 128 + k];
    out[g * 3 + tid] = s;
  }
}

// ---------------- host ----------------

extern "C" void kernel_launch(void* const* d_in, const int* in_sizes, int n_in,
                              void* d_out, int out_size, void* d_ws, size_t ws_size,
                              hipStream_t stream) {
  const float* feats  = (const float*)d_in[0];
  const float* W_edge = (const float*)d_in[1];
  const float* b_edge = (const float*)d_in[2];
  const float* gWih   = (const float*)d_in[3];
  const float* gWhh   = (const float*)d_in[4];
  const float* gbih   = (const float*)d_in[5];
  const float* gbhh   = (const float*)d_in[6];
  const float* lWi0   = (const float*)d_in[7];
  const float* lWh0   = (const float*)d_in[8];
  const float* lbi0   = (const float*)d_in[9];
  const float* lbh0   = (const float*)d_in[10];
  const float* lWi1   = (const float*)d_in[11];
  const float* lWh1   = (const float*)d_in[12];
  const float* lbi1   = (const float*)d_in[13];
  const float* lbh1   = (const float*)d_in[14];
  const float* lWi2   = (const float*)d_in[15];
  const float* lWh2   = (const float*)d_in[16];
  const float* lbi2   = (const float*)d_in[17];
  const float* lbh2   = (const float*)d_in[18];
  const float* Wp     = (const float*)d_in[19];
  const float* bp     = (const float*)d_in[20];
  const int* src      = (const int*)d_in[21];
  const int* dst      = (const int*)d_in[22];
  const int* ety      = (const int*)d_in[23];
  float* out = (float*)d_out;

  char* ws = (char*)d_ws;
  float* h      = (float*)ws;                    // 16,384,000 B
  float* a      = (float*)(ws + 16384000);       // 16,384,000 B
  u16*   Whb    = (u16*)(ws + 32768000);         // 49,152,000 B
  u32*   packed = (u32*)(ws + 81920000);         //  4,096,000 B
  float* wt_gru = (float*)(ws + 86016000);       //     98,304 B
  float* wtl    = (float*)(ws + 86114304);       //    458,752 B
  float* WTih0 = wtl;
  float* WThh0 = WTih0 + 32768;
  float* WTih1 = WThh0 + 16384;
  float* WThh1 = WTih1 + 16384;
  float* WTih2 = WThh1 + 16384;
  float* WThh2 = WTih2 + 16384;

  k_pack<<<NEDGE / 256, 256, 0, stream>>>(src, dst, ety, packed);
  k_transpose<<<48, 256, 0, stream>>>(gWih, wt_gru, 192, 64);
  k_transpose<<<48, 256, 0, stream>>>(gWhh, wt_gru + 12288, 192, 64);
  k_transpose<<<128, 256, 0, stream>>>(lWi0, WTih0, 256, 128);
  k_transpose<<<64, 256, 0, stream>>>(lWh0, WThh0, 256, 64);
  k_transpose<<<64, 256, 0, stream>>>(lWi1, WTih1, 256, 64);
  k_transpose<<<64, 256, 0, stream>>>(lWh1, WThh1, 256, 64);
  k_transpose<<<64, 256, 0, stream>>>(lWi2, WTih2, 256, 64);
  k_transpose<<<64, 256, 0, stream>>>(lWh2, WThh2, 256, 64);
  hipMemcpyAsync(h, feats, (size_t)N_NODES * DIM * sizeof(float),
                 hipMemcpyDeviceToDevice, stream);

  for (int s = 0; s < NSTEPS; s++) {
    k_wh<<<dim3(N_NODES / 64, 6), 256, 0, stream>>>(h, W_edge, b_edge, Whb);
    hipMemsetAsync(a, 0, (size_t)N_NODES * DIM * sizeof(float), stream);
    k_scatter<<<dim3(NGRAPH, 2), 512, 0, stream>>>(Whb, packed, a);
    k_gru<<<N_NODES / 32, 256, 0, stream>>>(a, h, wt_gru, gbih, gbhh);
  }
  k_set2set<<<NGRAPH, 256, 0, stream>>>(h, WTih0, WThh0, WTih1, WThh1, WTih2, WThh2,
                                        lbi0, lbh0, lbi1, lbh1, lbi2, lbh2, Wp, bp, out);
}

// Round 5
// 1936.439 us; speedup vs baseline: 2.0833x; 2.0002x over previous
//
#include <hip/hip_runtime.h>

typedef unsigned short u16;
typedef unsigned int u32;

#define N_NODES 64000
#define DIM 64
#define NGRAPH 320
#define NPG 200
#define NEDGE 1024000
#define EPG 3200
#define NSTEPS 5
#define NITERS 6

__device__ __forceinline__ float bf2f(u16 u) {
  u32 x = ((u32)u) << 16;
  float f;
  __builtin_memcpy(&f, &x, 4);
  return f;
}
__device__ __forceinline__ u16 f2bf(float f) {
  u32 x;
  __builtin_memcpy(&x, &f, 4);
  x = (x + 0x7FFFu + ((x >> 16) & 1u)) >> 16;
  return (u16)x;
}
__device__ __forceinline__ float sigmf(float x) { return 1.0f / (1.0f + __expf(-x)); }

// ---------------- prep kernels ----------------

// Counting-sort each graph's edges by destination, split into two sections:
// section A = etypes {0,1,2}, section B = {3,4,5} (B row offsets continue after A).
// rec = src_local | (etype_mod3 << 8), u16. Runs ONCE; reused by all 5 steps.
__global__ void __launch_bounds__(256) k_csr(const int* __restrict__ src,
                                             const int* __restrict__ dst,
                                             const int* __restrict__ ety,
                                             u16* __restrict__ recs,
                                             int* __restrict__ rowsA,
                                             int* __restrict__ rowsB) {
  __shared__ int cA[NPG], cB[NPG];
  __shared__ int rA[NPG + 1], rB[NPG + 1];
  int g = blockIdx.x, tid = threadIdx.x;
  int base = g * NPG;
  for (int i = tid; i < NPG; i += 256) { cA[i] = 0; cB[i] = 0; }
  __syncthreads();
  for (int e = tid; e < EPG; e += 256) {
    int d = dst[g * EPG + e] - base;
    int t = ety[g * EPG + e];
    atomicAdd(t < 3 ? &cA[d] : &cB[d], 1);
  }
  __syncthreads();
  if (tid == 0) {
    int s = 0;
    for (int n = 0; n < NPG; n++) { rA[n] = s; s += cA[n]; }
    rA[NPG] = s;
    for (int n = 0; n < NPG; n++) { rB[n] = s; s += cB[n]; }
    rB[NPG] = s;  // == EPG
  }
  __syncthreads();
  for (int i = tid; i < NPG; i += 256) { cA[i] = rA[i]; cB[i] = rB[i]; }
  __syncthreads();
  for (int e = tid; e < EPG; e += 256) {
    int d = dst[g * EPG + e] - base;
    int t = ety[g * EPG + e];
    int s = src[g * EPG + e] - base;
    int pos = atomicAdd(t < 3 ? &cA[d] : &cB[d], 1);
    recs[g * EPG + pos] = (u16)(s | ((t < 3 ? t : t - 3) << 8));
  }
  for (int i = tid; i <= NPG; i += 256) {
    rowsA[g * (NPG + 1) + i] = rA[i];
    rowsB[g * (NPG + 1) + i] = rB[i];
  }
}

__global__ void k_transpose(const float* __restrict__ src, float* __restrict__ dst, int R, int C) {
  int i = blockIdx.x * 256 + threadIdx.x;
  if (i < R * C) {
    int r = i / C, c = i - r * C;
    dst[c * R + r] = src[i];
  }
}

// ---------------- per-step kernels ----------------

// Wh[t][n][o] = sum_d h[n][d] * W_edge[t][d][o] + b_edge[t][o], stored bf16
__global__ void __launch_bounds__(256) k_wh(const float* __restrict__ h,
                                            const float* __restrict__ W_edge,
                                            const float* __restrict__ b_edge,
                                            u16* __restrict__ Whb) {
  __shared__ __align__(16) float h_s[64 * 64];
  int tid = threadIdx.x;
  int o = tid & 63, nl = tid >> 6;
  int t = blockIdx.y;
  int n0 = blockIdx.x * 64;
  for (int i = tid; i < 4096; i += 256) h_s[i] = h[(size_t)n0 * 64 + i];
  float wcol[64];
#pragma unroll
  for (int k = 0; k < 64; k++) wcol[k] = W_edge[(t * 64 + k) * 64 + o];
  float bias = b_edge[t * 64 + o];
  __syncthreads();
  for (int ng = 0; ng < 16; ng++) {
    int n = ng * 4 + nl;
    float acc = bias;
#pragma unroll
    for (int k4 = 0; k4 < 16; k4++) {
      float4 hv = *(const float4*)&h_s[n * 64 + k4 * 4];
      acc += hv.x * wcol[k4 * 4] + hv.y * wcol[k4 * 4 + 1] +
             hv.z * wcol[k4 * 4 + 2] + hv.w * wcol[k4 * 4 + 3];
    }
    Whb[((size_t)t * N_NODES + n0 + n) * 64 + o] = f2bf(acc);
  }
}

// v5: CSR gather, NO atomics. One block per graph, 512 threads (8 waves).
// Wave w owns dst nodes {w, w+8, ...} (25 each), lane = feature dim.
// Two phases: stage etypes 0-2 / 3-5 of this graph's Whb slice into LDS, then
// per owned node, sum its in-edges' rows from LDS into a register accumulator.
__global__ void __launch_bounds__(512) k_scatter(const u16* __restrict__ Whb,
                                                 const u16* __restrict__ recs,
                                                 const int* __restrict__ rowsA,
                                                 const int* __restrict__ rowsB,
                                                 float* __restrict__ a) {
  __shared__ u16 wh_s[3 * NPG * 64];   // 76,800 B
  __shared__ u16 rec_s[EPG];           //  6,400 B
  __shared__ int rowA_s[NPG + 1];
  __shared__ int rowB_s[NPG + 1];
  int g = blockIdx.x;
  int tid = threadIdx.x, lane = tid & 63, wid = tid >> 6;
  size_t nodebase = (size_t)g * NPG;
  {
    const u32* r32 = (const u32*)(recs + g * EPG);
    u32* rs32 = (u32*)rec_s;
    for (int i = tid; i < EPG / 2; i += 512) rs32[i] = r32[i];
  }
  for (int i = tid; i <= NPG; i += 512) {
    rowA_s[i] = rowsA[g * (NPG + 1) + i];
    rowB_s[i] = rowsB[g * (NPG + 1) + i];
  }
  float acc_r[25];
#pragma unroll
  for (int q = 0; q < 25; q++) acc_r[q] = 0.f;
  for (int ph = 0; ph < 2; ph++) {
    __syncthreads();  // previous phase's readers done before overwriting wh_s
    {
      u32* ws32 = (u32*)wh_s;
      for (int t = 0; t < 3; t++) {
        const u32* s32 = (const u32*)(Whb + ((size_t)(ph * 3 + t) * N_NODES + nodebase) * 64);
        for (int i = tid; i < NPG * 32; i += 512) ws32[t * NPG * 32 + i] = s32[i];
      }
    }
    __syncthreads();
    const int* row = ph ? rowB_s : rowA_s;
    for (int q = 0; q < 25; q++) {
      int n = q * 8 + wid;
      int rs = row[n], re = row[n + 1];
      float r = 0.f;
      int e = rs;
      for (; e + 4 <= re; e += 4) {
        int p0 = rec_s[e], p1 = rec_s[e + 1], p2 = rec_s[e + 2], p3 = rec_s[e + 3];
        float v0 = bf2f(wh_s[((p0 >> 8) * NPG + (p0 & 255)) * 64 + lane]);
        float v1 = bf2f(wh_s[((p1 >> 8) * NPG + (p1 & 255)) * 64 + lane]);
        float v2 = bf2f(wh_s[((p2 >> 8) * NPG + (p2 & 255)) * 64 + lane]);
        float v3 = bf2f(wh_s[((p3 >> 8) * NPG + (p3 & 255)) * 64 + lane]);
        r += v0 + v1 + v2 + v3;
      }
      for (; e < re; e++) {
        int p = rec_s[e];
        r += bf2f(wh_s[((p >> 8) * NPG + (p & 255)) * 64 + lane]);
      }
      acc_r[q] += r;
    }
  }
  float* ag = a + nodebase * 64;
#pragma unroll
  for (int q = 0; q < 25; q++) {
    int n = q * 8 + wid;
    ag[n * 64 + lane] = acc_r[q];
  }
}

// GRU: gi = a@W_ih^T + b_ih; gh = h@W_hh^T + b_hh; gate math; h updated in place.
__global__ void __launch_bounds__(256) k_gru(const float* __restrict__ a,
                                             float* __restrict__ h,
                                             const float* __restrict__ wt_gru,
                                             const float* __restrict__ b_ih,
                                             const float* __restrict__ b_hh) {
  __shared__ __align__(16) float a_s[32 * 64];
  __shared__ __align__(16) float h_s[32 * 64];
  __shared__ float gsum[32 * 192];
  __shared__ float ghn[32 * 64];
  int tid = threadIdx.x;
  int nb = blockIdx.x * 32;
  for (int i = tid; i < 2048; i += 256) {
    a_s[i] = a[(size_t)nb * 64 + i];
    h_s[i] = h[(size_t)nb * 64 + i];
  }
  float wih[64], whh[64];
  float bi = 0.f, bh = 0.f;
  int j = tid;
  if (j < 192) {
    bi = b_ih[j];
    bh = b_hh[j];
#pragma unroll
    for (int k = 0; k < 64; k++) {
      wih[k] = wt_gru[k * 192 + j];
      whh[k] = wt_gru[12288 + k * 192 + j];
    }
  }
  __syncthreads();
  if (j < 192) {
    for (int n = 0; n < 32; n++) {
      float gi = bi, gh = bh;
#pragma unroll
      for (int k4 = 0; k4 < 16; k4++) {
        float4 av = *(const float4*)&a_s[n * 64 + k4 * 4];
        float4 hv = *(const float4*)&h_s[n * 64 + k4 * 4];
        gi += av.x * wih[k4 * 4] + av.y * wih[k4 * 4 + 1] + av.z * wih[k4 * 4 + 2] + av.w * wih[k4 * 4 + 3];
        gh += hv.x * whh[k4 * 4] + hv.y * whh[k4 * 4 + 1] + hv.z * whh[k4 * 4 + 2] + hv.w * whh[k4 * 4 + 3];
      }
      if (j < 128) {
        gsum[n * 192 + j] = gi + gh;
      } else {
        gsum[n * 192 + j] = gi;
        ghn[n * 64 + (j - 128)] = gh;
      }
    }
  }
  __syncthreads();
  int d = tid & 63, nl = tid >> 6;
  for (int q = 0; q < 8; q++) {
    int n = q * 4 + nl;
    float r = sigmf(gsum[n * 192 + d]);
    float z = sigmf(gsum[n * 192 + 64 + d]);
    float gg = tanhf(gsum[n * 192 + 128 + d] + r * ghn[n * 64 + d]);
    float hv = h_s[n * 64 + d];
    h[(size_t)(nb + n) * 64 + d] = (1.0f - z) * gg + z * hv;
  }
}

// ---------------- Set2Set: one block per graph, all 6 iterations internal ----------------

__global__ void __launch_bounds__(256) k_set2set(
    const float* __restrict__ feat,
    const float* __restrict__ WTih0, const float* __restrict__ WThh0,
    const float* __restrict__ WTih1, const float* __restrict__ WThh1,
    const float* __restrict__ WTih2, const float* __restrict__ WThh2,
    const float* __restrict__ b_ih0, const float* __restrict__ b_hh0,
    const float* __restrict__ b_ih1, const float* __restrict__ b_hh1,
    const float* __restrict__ b_ih2, const float* __restrict__ b_hh2,
    const float* __restrict__ Wp, const float* __restrict__ bp,
    float* __restrict__ out) {
  __shared__ __align__(16) float feat_s[NPG * 64];
  __shared__ float qstar[128];
  __shared__ float xbuf[128];
  __shared__ float hs_s[3][64];
  __shared__ float cs_s[3][64];
  __shared__ float gates[256];
  __shared__ float e_s[NPG];
  __shared__ float red[4][64];
  __shared__ float scal[2];
  int tid = threadIdx.x;
  int g = blockIdx.x;
  int lane = tid & 63, wid = tid >> 6;
  for (int i = tid; i < NPG * 64; i += 256) feat_s[i] = feat[(size_t)g * NPG * 64 + i];
  if (tid < 128) { qstar[tid] = 0.f; xbuf[tid] = 0.f; }
  if (tid < 64) {
    for (int l = 0; l < 3; l++) { hs_s[l][tid] = 0.f; cs_s[l][tid] = 0.f; }
  }
  __syncthreads();
  for (int it = 0; it < NITERS; it++) {
    {
      float gj = b_ih0[tid] + b_hh0[tid];
      for (int k = 0; k < 128; k++) gj += qstar[k] * WTih0[k * 256 + tid];
      for (int k = 0; k < 64; k++) gj += hs_s[0][k] * WThh0[k * 256 + tid];
      gates[tid] = gj;
    }
    __syncthreads();
    if (tid < 64) {
      float c = sigmf(gates[64 + tid]) * cs_s[0][tid] + sigmf(gates[tid]) * tanhf(gates[128 + tid]);
      float x = sigmf(gates[192 + tid]) * tanhf(c);
      cs_s[0][tid] = c; hs_s[0][tid] = x; xbuf[tid] = x;
    }
    __syncthreads();
    for (int l = 1; l < 3; l++) {
      const float* Wi = (l == 1) ? WTih1 : WTih2;
      const float* Wh = (l == 1) ? WThh1 : WThh2;
      const float* bi = (l == 1) ? b_ih1 : b_ih2;
      const float* bh = (l == 1) ? b_hh1 : b_hh2;
      float gj = bi[tid] + bh[tid];
      for (int k = 0; k < 64; k++)
        gj += xbuf[k] * Wi[k * 256 + tid] + hs_s[l][k] * Wh[k * 256 + tid];
      gates[tid] = gj;
      __syncthreads();
      if (tid < 64) {
        float c = sigmf(gates[64 + tid]) * cs_s[l][tid] + sigmf(gates[tid]) * tanhf(gates[128 + tid]);
        float x = sigmf(gates[192 + tid]) * tanhf(c);
        cs_s[l][tid] = c; hs_s[l][tid] = x; xbuf[tid] = x;
      }
      __syncthreads();
    }
    for (int n = wid; n < NPG; n += 4) {
      float v = feat_s[n * 64 + lane] * xbuf[lane];
      for (int off = 32; off > 0; off >>= 1) v += __shfl_down(v, off);
      if (lane == 0) e_s[n] = v;
    }
    __syncthreads();
    if (tid < 64) {
      float m = -1e30f;
      for (int n = lane; n < NPG; n += 64) m = fmaxf(m, e_s[n]);
      for (int off = 32; off > 0; off >>= 1) m = fmaxf(m, __shfl_down(m, off));
      m = __shfl(m, 0);
      float ssum = 0.f;
      for (int n = lane; n < NPG; n += 64) {
        float ex = __expf(e_s[n] - m);
        e_s[n] = ex;
        ssum += ex;
      }
      for (int off = 32; off > 0; off >>= 1) ssum += __shfl_down(ssum, off);
      if (lane == 0) scal[0] = ssum;
    }
    __syncthreads();
    float denom = scal[0];
    {
      float r = 0.f;
      for (int n = wid; n < NPG; n += 4) r += feat_s[n * 64 + lane] * e_s[n];
      red[wid][lane] = r;
    }
    __syncthreads();
    if (tid < 64) {
      float ro = (red[0][lane] + red[1][lane] + red[2][lane] + red[3][lane]) / denom;
      qstar[lane] = xbuf[lane];
      qstar[64 + lane] = ro;
    }
    __syncthreads();
  }
  if (tid < 3) {
    float s = bp[tid];
    for (int k = 0; k < 128; k++) s += qstar[k] * Wp[tid * 128 + k];
    out[g * 3 + tid] = s;
  }
}

// ---------------- host ----------------

extern "C" void kernel_launch(void* const* d_in, const int* in_sizes, int n_in,
                              void* d_out, int out_size, void* d_ws, size_t ws_size,
                              hipStream_t stream) {
  const float* feats  = (const float*)d_in[0];
  const float* W_edge = (const float*)d_in[1];
  const float* b_edge = (const float*)d_in[2];
  const float* gWih   = (const float*)d_in[3];
  const float* gWhh   = (const float*)d_in[4];
  const float* gbih   = (const float*)d_in[5];
  const float* gbhh   = (const float*)d_in[6];
  const float* lWi0   = (const float*)d_in[7];
  const float* lWh0   = (const float*)d_in[8];
  const float* lbi0   = (const float*)d_in[9];
  const float* lbh0   = (const float*)d_in[10];
  const float* lWi1   = (const float*)d_in[11];
  const float* lWh1   = (const float*)d_in[12];
  const float* lbi1   = (const float*)d_in[13];
  const float* lbh1   = (const float*)d_in[14];
  const float* lWi2   = (const float*)d_in[15];
  const float* lWh2   = (const float*)d_in[16];
  const float* lbi2   = (const float*)d_in[17];
  const float* lbh2   = (const float*)d_in[18];
  const float* Wp     = (const float*)d_in[19];
  const float* bp     = (const float*)d_in[20];
  const int* src      = (const int*)d_in[21];
  const int* dst      = (const int*)d_in[22];
  const int* ety      = (const int*)d_in[23];
  float* out = (float*)d_out;

  char* ws = (char*)d_ws;
  float* h      = (float*)ws;                    // 16,384,000 B
  float* a      = (float*)(ws + 16384000);       // 16,384,000 B
  u16*   Whb    = (u16*)(ws + 32768000);         // 49,152,000 B
  u16*   recs   = (u16*)(ws + 81920000);         //  2,048,000 B
  int*   rowsA  = (int*)(ws + 83968000);         //    257,280 B
  int*   rowsB  = (int*)(ws + 84225280);         //    257,280 B
  float* wt_gru = (float*)(ws + 86016000);       //     98,304 B
  float* wtl    = (float*)(ws + 86114304);       //    458,752 B
  float* WTih0 = wtl;
  float* WThh0 = WTih0 + 32768;
  float* WTih1 = WThh0 + 16384;
  float* WThh1 = WTih1 + 16384;
  float* WTih2 = WThh1 + 16384;
  float* WThh2 = WTih2 + 16384;

  k_csr<<<NGRAPH, 256, 0, stream>>>(src, dst, ety, recs, rowsA, rowsB);
  k_transpose<<<48, 256, 0, stream>>>(gWih, wt_gru, 192, 64);
  k_transpose<<<48, 256, 0, stream>>>(gWhh, wt_gru + 12288, 192, 64);
  k_transpose<<<128, 256, 0, stream>>>(lWi0, WTih0, 256, 128);
  k_transpose<<<64, 256, 0, stream>>>(lWh0, WThh0, 256, 64);
  k_transpose<<<64, 256, 0, stream>>>(lWi1, WTih1, 256, 64);
  k_transpose<<<64, 256, 0, stream>>>(lWh1, WThh1, 256, 64);
  k_transpose<<<64, 256, 0, stream>>>(lWi2, WTih2, 256, 64);
  k_transpose<<<64, 256, 0, stream>>>(lWh2, WThh2, 256, 64);
  hipMemcpyAsync(h, feats, (size_t)N_NODES * DIM * sizeof(float),
                 hipMemcpyDeviceToDevice, stream);

  for (int s = 0; s < NSTEPS; s++) {
    k_wh<<<dim3(N_NODES / 64, 6), 256, 0, stream>>>(h, W_edge, b_edge, Whb);
    k_scatter<<<NGRAPH, 512, 0, stream>>>(Whb, recs, rowsA, rowsB, a);
    k_gru<<<N_NODES / 32, 256, 0, stream>>>(a, h, wt_gru, gbih, gbhh);
  }
  k_set2set<<<NGRAPH, 256, 0, stream>>>(h, WTih0, WThh0, WTih1, WThh1, WTih2, WThh2,
                                        lbi0, lbh0, lbi1, lbh1, lbi2, lbh2, Wp, bp, out);
}

// Round 6
// 1912.044 us; speedup vs baseline: 2.1098x; 1.0128x over previous
//
#include <hip/hip_runtime.h>

typedef unsigned short u16;
typedef unsigned int u32;

#define N_NODES 64000
#define DIM 64
#define NGRAPH 320
#define NPG 200
#define NEDGE 1024000
#define EPG 3200
#define NSTEPS 5
#define NITERS 6

typedef __attribute__((ext_vector_type(8))) short bf16x8;
typedef __attribute__((ext_vector_type(4))) float f32x4;

__device__ __forceinline__ float bf2f(u16 u) {
  u32 x = ((u32)u) << 16;
  float f;
  __builtin_memcpy(&f, &x, 4);
  return f;
}
__device__ __forceinline__ u16 f2bf(float f) {
  u32 x;
  __builtin_memcpy(&x, &f, 4);
  x = (x + 0x7FFFu + ((x >> 16) & 1u)) >> 16;
  return (u16)x;
}
__device__ __forceinline__ float sigmf(float x) { return 1.0f / (1.0f + __expf(-x)); }

// ---------------- prep kernels ----------------

__global__ void __launch_bounds__(256) k_csr(const int* __restrict__ src,
                                             const int* __restrict__ dst,
                                             const int* __restrict__ ety,
                                             u16* __restrict__ recs,
                                             int* __restrict__ rowsA,
                                             int* __restrict__ rowsB) {
  __shared__ int cA[NPG], cB[NPG];
  __shared__ int rA[NPG + 1], rB[NPG + 1];
  int g = blockIdx.x, tid = threadIdx.x;
  int base = g * NPG;
  for (int i = tid; i < NPG; i += 256) { cA[i] = 0; cB[i] = 0; }
  __syncthreads();
  for (int e = tid; e < EPG; e += 256) {
    int d = dst[g * EPG + e] - base;
    int t = ety[g * EPG + e];
    atomicAdd(t < 3 ? &cA[d] : &cB[d], 1);
  }
  __syncthreads();
  if (tid == 0) {
    int s = 0;
    for (int n = 0; n < NPG; n++) { rA[n] = s; s += cA[n]; }
    rA[NPG] = s;
    for (int n = 0; n < NPG; n++) { rB[n] = s; s += cB[n]; }
    rB[NPG] = s;
  }
  __syncthreads();
  for (int i = tid; i < NPG; i += 256) { cA[i] = rA[i]; cB[i] = rB[i]; }
  __syncthreads();
  for (int e = tid; e < EPG; e += 256) {
    int d = dst[g * EPG + e] - base;
    int t = ety[g * EPG + e];
    int s = src[g * EPG + e] - base;
    int pos = atomicAdd(t < 3 ? &cA[d] : &cB[d], 1);
    recs[g * EPG + pos] = (u16)(s | ((t < 3 ? t : t - 3) << 8));
  }
  for (int i = tid; i <= NPG; i += 256) {
    rowsA[g * (NPG + 1) + i] = rA[i];
    rowsB[g * (NPG + 1) + i] = rB[i];
  }
}

__global__ void k_transpose(const float* __restrict__ src, float* __restrict__ dst, int R, int C) {
  int i = blockIdx.x * 256 + threadIdx.x;
  if (i < R * C) {
    int r = i / C, c = i - r * C;
    dst[c * R + r] = src[i];
  }
}

// fp32 -> bf16 same layout
__global__ void k_cvt(const float* __restrict__ src, u16* __restrict__ dst, int n) {
  int i = blockIdx.x * 256 + threadIdx.x;
  if (i < n) dst[i] = f2bf(src[i]);
}

// W_edge [t][k][o] fp32  ->  WeT [t][o][k] bf16 (k contiguous for B-fragments)
__global__ void k_cvt_weT(const float* __restrict__ W_edge, u16* __restrict__ WeT) {
  int i = blockIdx.x * 256 + threadIdx.x;
  if (i < 6 * 64 * 64) {
    int t = i >> 12, rem = i & 4095;
    int o = rem >> 6, k = rem & 63;
    WeT[i] = f2bf(W_edge[t * 4096 + k * 64 + o]);
  }
}

// ---------------- per-step kernels ----------------

// MFMA Wh: Whb[t][n][o] = sum_k hb[n][k] * WeT[t][o][k] + b_edge[t][o]  (bf16 out)
// 1000 blocks x 256 thr; wave w covers 16 nodes; A-frags from global hb,
// B-frags from global WeT (L2-hot). No LDS.
__global__ void __launch_bounds__(256) k_wh_mfma(const u16* __restrict__ hb,
                                                 const u16* __restrict__ WeT,
                                                 const float* __restrict__ b_edge,
                                                 u16* __restrict__ Whb) {
  int tid = threadIdx.x;
  int lane = tid & 63, w = tid >> 6;
  int m = lane & 15, quad = lane >> 4;
  int nb = blockIdx.x * 64 + w * 16;
  const u16* ap = hb + (size_t)(nb + m) * 64 + quad * 8;
  bf16x8 a0 = *(const bf16x8*)ap;
  bf16x8 a1 = *(const bf16x8*)(ap + 32);
#pragma unroll
  for (int t = 0; t < 6; t++) {
#pragma unroll
    for (int ot = 0; ot < 4; ot++) {
      const u16* bp = WeT + ((t * 64 + ot * 16 + m) * 64) + quad * 8;
      bf16x8 b0 = *(const bf16x8*)bp;
      bf16x8 b1 = *(const bf16x8*)(bp + 32);
      f32x4 c = {0.f, 0.f, 0.f, 0.f};
      c = __builtin_amdgcn_mfma_f32_16x16x32_bf16(a0, b0, c, 0, 0, 0);
      c = __builtin_amdgcn_mfma_f32_16x16x32_bf16(a1, b1, c, 0, 0, 0);
      float bias = b_edge[t * 64 + ot * 16 + m];
#pragma unroll
      for (int r = 0; r < 4; r++) {
        int node = nb + quad * 4 + r;
        Whb[((size_t)t * N_NODES + node) * 64 + ot * 16 + m] = f2bf(c[r] + bias);
      }
    }
  }
}

// CSR gather scatter (unchanged structure), output ab in bf16 for the GRU GEMM.
__global__ void __launch_bounds__(512) k_scatter(const u16* __restrict__ Whb,
                                                 const u16* __restrict__ recs,
                                                 const int* __restrict__ rowsA,
                                                 const int* __restrict__ rowsB,
                                                 u16* __restrict__ ab) {
  __shared__ u16 wh_s[3 * NPG * 64];
  __shared__ u16 rec_s[EPG];
  __shared__ int rowA_s[NPG + 1];
  __shared__ int rowB_s[NPG + 1];
  int g = blockIdx.x;
  int tid = threadIdx.x, lane = tid & 63, wid = tid >> 6;
  size_t nodebase = (size_t)g * NPG;
  {
    const u32* r32 = (const u32*)(recs + g * EPG);
    u32* rs32 = (u32*)rec_s;
    for (int i = tid; i < EPG / 2; i += 512) rs32[i] = r32[i];
  }
  for (int i = tid; i <= NPG; i += 512) {
    rowA_s[i] = rowsA[g * (NPG + 1) + i];
    rowB_s[i] = rowsB[g * (NPG + 1) + i];
  }
  float acc_r[25];
#pragma unroll
  for (int q = 0; q < 25; q++) acc_r[q] = 0.f;
  for (int ph = 0; ph < 2; ph++) {
    __syncthreads();
    {
      u32* ws32 = (u32*)wh_s;
      for (int t = 0; t < 3; t++) {
        const u32* s32 = (const u32*)(Whb + ((size_t)(ph * 3 + t) * N_NODES + nodebase) * 64);
        for (int i = tid; i < NPG * 32; i += 512) ws32[t * NPG * 32 + i] = s32[i];
      }
    }
    __syncthreads();
    const int* row = ph ? rowB_s : rowA_s;
    for (int q = 0; q < 25; q++) {
      int n = q * 8 + wid;
      int rs = row[n], re = row[n + 1];
      float r = 0.f;
      int e = rs;
      for (; e + 4 <= re; e += 4) {
        int p0 = rec_s[e], p1 = rec_s[e + 1], p2 = rec_s[e + 2], p3 = rec_s[e + 3];
        float v0 = bf2f(wh_s[((p0 >> 8) * NPG + (p0 & 255)) * 64 + lane]);
        float v1 = bf2f(wh_s[((p1 >> 8) * NPG + (p1 & 255)) * 64 + lane]);
        float v2 = bf2f(wh_s[((p2 >> 8) * NPG + (p2 & 255)) * 64 + lane]);
        float v3 = bf2f(wh_s[((p3 >> 8) * NPG + (p3 & 255)) * 64 + lane]);
        r += v0 + v1 + v2 + v3;
      }
      for (; e < re; e++) {
        int p = rec_s[e];
        r += bf2f(wh_s[((p >> 8) * NPG + (p & 255)) * 64 + lane]);
      }
      acc_r[q] += r;
    }
  }
  u16* ag = ab + nodebase * 64;
#pragma unroll
  for (int q = 0; q < 25; q++) {
    int n = q * 8 + wid;
    ag[n * 64 + lane] = f2bf(acc_r[q]);
  }
}

// MFMA GRU: gi = ab@Wih^T, gh = hb@Whh^T via 16x16x32 bf16 MFMA into LDS,
// fp32 gate epilogue updates h (fp32) and hb (bf16) in place.
__global__ void __launch_bounds__(256) k_gru_mfma(const u16* __restrict__ ab,
                                                  u16* __restrict__ hb,
                                                  float* __restrict__ h,
                                                  const u16* __restrict__ Wihb,
                                                  const u16* __restrict__ Whhb,
                                                  const float* __restrict__ b_ih,
                                                  const float* __restrict__ b_hh) {
  __shared__ float gsum[64 * 192];  // gi (no bias)
  __shared__ float ghs[64 * 192];   // gh (no bias)
  int tid = threadIdx.x;
  int lane = tid & 63, w = tid >> 6;
  int m = lane & 15, quad = lane >> 4;
  int nb = blockIdx.x * 64 + w * 16;
  const u16* aap = ab + (size_t)(nb + m) * 64 + quad * 8;
  const u16* ahp = hb + (size_t)(nb + m) * 64 + quad * 8;
  bf16x8 aa0 = *(const bf16x8*)aap;
  bf16x8 aa1 = *(const bf16x8*)(aap + 32);
  bf16x8 ah0 = *(const bf16x8*)ahp;
  bf16x8 ah1 = *(const bf16x8*)(ahp + 32);
#pragma unroll
  for (int jt = 0; jt < 12; jt++) {
    const u16* bip = Wihb + (jt * 16 + m) * 64 + quad * 8;
    const u16* bhp = Whhb + (jt * 16 + m) * 64 + quad * 8;
    bf16x8 bi0 = *(const bf16x8*)bip;
    bf16x8 bi1 = *(const bf16x8*)(bip + 32);
    bf16x8 bh0 = *(const bf16x8*)bhp;
    bf16x8 bh1 = *(const bf16x8*)(bhp + 32);
    f32x4 ci = {0.f, 0.f, 0.f, 0.f};
    ci = __builtin_amdgcn_mfma_f32_16x16x32_bf16(aa0, bi0, ci, 0, 0, 0);
    ci = __builtin_amdgcn_mfma_f32_16x16x32_bf16(aa1, bi1, ci, 0, 0, 0);
    f32x4 ch = {0.f, 0.f, 0.f, 0.f};
    ch = __builtin_amdgcn_mfma_f32_16x16x32_bf16(ah0, bh0, ch, 0, 0, 0);
    ch = __builtin_amdgcn_mfma_f32_16x16x32_bf16(ah1, bh1, ch, 0, 0, 0);
#pragma unroll
    for (int r = 0; r < 4; r++) {
      int n = w * 16 + quad * 4 + r;
      gsum[n * 192 + jt * 16 + m] = ci[r];
      ghs[n * 192 + jt * 16 + m] = ch[r];
    }
  }
  __syncthreads();
  int d = tid & 63, nl = tid >> 6;
  float bi_r = b_ih[d], bh_r = b_hh[d];
  float bi_z = b_ih[64 + d], bh_z = b_hh[64 + d];
  float bi_n = b_ih[128 + d], bh_n = b_hh[128 + d];
#pragma unroll
  for (int q = 0; q < 16; q++) {
    int n = q * 4 + nl;
    int base = n * 192 + d;
    float r = sigmf(gsum[base] + bi_r + ghs[base] + bh_r);
    float z = sigmf(gsum[base + 64] + bi_z + ghs[base + 64] + bh_z);
    float ng = tanhf(gsum[base + 128] + bi_n + r * (ghs[base + 128] + bh_n));
    size_t gidx = (size_t)(blockIdx.x * 64 + n) * 64 + d;
    float hv = h[gidx];
    float hn = (1.0f - z) * ng + z * hv;
    h[gidx] = hn;
    hb[gidx] = f2bf(hn);
  }
}

// ---------------- Set2Set: 1024 threads/block, split-K matvecs ----------------

__global__ void __launch_bounds__(1024) k_set2set(
    const float* __restrict__ feat,
    const float* __restrict__ WTih0, const float* __restrict__ WThh0,
    const float* __restrict__ WTih1, const float* __restrict__ WThh1,
    const float* __restrict__ WTih2, const float* __restrict__ WThh2,
    const float* __restrict__ b_ih0, const float* __restrict__ b_hh0,
    const float* __restrict__ b_ih1, const float* __restrict__ b_hh1,
    const float* __restrict__ b_ih2, const float* __restrict__ b_hh2,
    const float* __restrict__ Wp, const float* __restrict__ bp,
    float* __restrict__ out) {
  __shared__ __align__(16) float feat_s[NPG * 64];
  __shared__ float qstar[128];
  __shared__ float xbuf[64];
  __shared__ float hs_s[3][64];
  __shared__ float cs_s[3][64];
  __shared__ float gates[256];
  __shared__ float gpart[4 * 256];
  __shared__ float e_s[NPG];
  __shared__ float red[16][64];
  __shared__ float scal[2];
  int tid = threadIdx.x;
  int g = blockIdx.x;
  int lane = tid & 63, wid = tid >> 6;
  int j = tid & 255, part = tid >> 8;
  for (int i = tid; i < NPG * 64; i += 1024) feat_s[i] = feat[(size_t)g * NPG * 64 + i];
  if (tid < 128) qstar[tid] = 0.f;
  if (tid < 64) {
    xbuf[tid] = 0.f;
    for (int l = 0; l < 3; l++) { hs_s[l][tid] = 0.f; cs_s[l][tid] = 0.f; }
  }
  __syncthreads();
  for (int it = 0; it < NITERS; it++) {
    // ---- LSTM layer 0: K = 192 (qstar 128 | hs0 64), 4-way split ----
    {
      float p = 0.f;
      int k0 = part * 48;
      for (int k = k0; k < k0 + 48; k++) {
        if (k < 128) p += qstar[k] * WTih0[k * 256 + j];
        else p += hs_s[0][k - 128] * WThh0[(k - 128) * 256 + j];
      }
      gpart[part * 256 + j] = p;
    }
    __syncthreads();
    if (tid < 256) {
      gates[tid] = gpart[tid] + gpart[256 + tid] + gpart[512 + tid] + gpart[768 + tid] +
                   b_ih0[tid] + b_hh0[tid];
    }
    __syncthreads();
    if (tid < 64) {
      float c = sigmf(gates[64 + tid]) * cs_s[0][tid] + sigmf(gates[tid]) * tanhf(gates[128 + tid]);
      float x = sigmf(gates[192 + tid]) * tanhf(c);
      cs_s[0][tid] = c; hs_s[0][tid] = x; xbuf[tid] = x;
    }
    __syncthreads();
    // ---- LSTM layers 1,2: K = 128 (xbuf 64 | hs_l 64), 4-way split ----
    for (int l = 1; l < 3; l++) {
      const float* Wi = (l == 1) ? WTih1 : WTih2;
      const float* Wh = (l == 1) ? WThh1 : WThh2;
      const float* bi = (l == 1) ? b_ih1 : b_ih2;
      const float* bh = (l == 1) ? b_hh1 : b_hh2;
      float p = 0.f;
      int k0 = part * 32;
      for (int k = k0; k < k0 + 32; k++) {
        if (k < 64) p += xbuf[k] * Wi[k * 256 + j];
        else p += hs_s[l][k - 64] * Wh[(k - 64) * 256 + j];
      }
      gpart[part * 256 + j] = p;
      __syncthreads();
      if (tid < 256) {
        gates[tid] = gpart[tid] + gpart[256 + tid] + gpart[512 + tid] + gpart[768 + tid] +
                     bi[tid] + bh[tid];
      }
      __syncthreads();
      if (tid < 64) {
        float c = sigmf(gates[64 + tid]) * cs_s[l][tid] + sigmf(gates[tid]) * tanhf(gates[128 + tid]);
        float x = sigmf(gates[192 + tid]) * tanhf(c);
        cs_s[l][tid] = c; hs_s[l][tid] = x; xbuf[tid] = x;
      }
      __syncthreads();
    }
    // ---- attention: e_n = dot(feat[n], q), 16 node-groups ----
    for (int n = wid; n < NPG; n += 16) {
      float v = feat_s[n * 64 + lane] * xbuf[lane];
      for (int off = 32; off > 0; off >>= 1) v += __shfl_down(v, off);
      if (lane == 0) e_s[n] = v;
    }
    __syncthreads();
    if (tid < 64) {
      float mx = -1e30f;
      for (int n = lane; n < NPG; n += 64) mx = fmaxf(mx, e_s[n]);
      for (int off = 32; off > 0; off >>= 1) mx = fmaxf(mx, __shfl_down(mx, off));
      mx = __shfl(mx, 0);
      float ssum = 0.f;
      for (int n = lane; n < NPG; n += 64) {
        float ex = __expf(e_s[n] - mx);
        e_s[n] = ex;
        ssum += ex;
      }
      for (int off = 32; off > 0; off >>= 1) ssum += __shfl_down(ssum, off);
      if (lane == 0) scal[0] = ssum;
    }
    __syncthreads();
    float denom = scal[0];
    {
      float r = 0.f;
      for (int n = wid; n < NPG; n += 16) r += feat_s[n * 64 + lane] * e_s[n];
      red[wid][lane] = r;
    }
    __syncthreads();
    if (tid < 64) {
      float ro = 0.f;
#pragma unroll
      for (int ww = 0; ww < 16; ww++) ro += red[ww][lane];
      qstar[lane] = xbuf[lane];
      qstar[64 + lane] = ro / denom;
    }
    __syncthreads();
  }
  if (tid < 3) {
    float s = bp[tid];
    for (int k = 0; k < 128; k++) s += qstar[k] * Wp[tid * 128 + k];
    out[g * 3 + tid] = s;
  }
}

// ---------------- host ----------------

extern "C" void kernel_launch(void* const* d_in, const int* in_sizes, int n_in,
                              void* d_out, int out_size, void* d_ws, size_t ws_size,
                              hipStream_t stream) {
  const float* feats  = (const float*)d_in[0];
  const float* W_edge = (const float*)d_in[1];
  const float* b_edge = (const float*)d_in[2];
  const float* gWih   = (const float*)d_in[3];
  const float* gWhh   = (const float*)d_in[4];
  const float* gbih   = (const float*)d_in[5];
  const float* gbhh   = (const float*)d_in[6];
  const float* lWi0   = (const float*)d_in[7];
  const float* lWh0   = (const float*)d_in[8];
  const float* lbi0   = (const float*)d_in[9];
  const float* lbh0   = (const float*)d_in[10];
  const float* lWi1   = (const float*)d_in[11];
  const float* lWh1   = (const float*)d_in[12];
  const float* lbi1   = (const float*)d_in[13];
  const float* lbh1   = (const float*)d_in[14];
  const float* lWi2   = (const float*)d_in[15];
  const float* lWh2   = (const float*)d_in[16];
  const float* lbi2   = (const float*)d_in[17];
  const float* lbh2   = (const float*)d_in[18];
  const float* Wp     = (const float*)d_in[19];
  const float* bp     = (const float*)d_in[20];
  const int* src      = (const int*)d_in[21];
  const int* dst      = (const int*)d_in[22];
  const int* ety      = (const int*)d_in[23];
  float* out = (float*)d_out;

  char* ws = (char*)d_ws;
  float* h      = (float*)ws;                    // 16,384,000 B
  u16*   hb     = (u16*)(ws + 16384000);         //  8,192,000 B
  u16*   ab     = (u16*)(ws + 24576000);         //  8,192,000 B
  u16*   Whb    = (u16*)(ws + 32768000);         // 49,152,000 B
  u16*   recs   = (u16*)(ws + 81920000);         //  2,048,000 B
  int*   rowsA  = (int*)(ws + 83968000);         //    257,280 B
  int*   rowsB  = (int*)(ws + 84225280);         //    257,280 B
  u16*   WeTb   = (u16*)(ws + 84482560);         //     49,152 B
  u16*   Wihb   = (u16*)(ws + 84531712);         //     24,576 B
  u16*   Whhb   = (u16*)(ws + 84556288);         //     24,576 B
  float* wtl    = (float*)(ws + 84580864);       //    458,752 B
  float* WTih0 = wtl;
  float* WThh0 = WTih0 + 32768;
  float* WTih1 = WThh0 + 16384;
  float* WThh1 = WTih1 + 16384;
  float* WTih2 = WThh1 + 16384;
  float* WThh2 = WTih2 + 16384;

  k_csr<<<NGRAPH, 256, 0, stream>>>(src, dst, ety, recs, rowsA, rowsB);
  k_cvt<<<(N_NODES * DIM + 255) / 256, 256, 0, stream>>>(feats, hb, N_NODES * DIM);
  k_cvt<<<48, 256, 0, stream>>>(gWih, Wihb, 12288);
  k_cvt<<<48, 256, 0, stream>>>(gWhh, Whhb, 12288);
  k_cvt_weT<<<96, 256, 0, stream>>>(W_edge, WeTb);
  k_transpose<<<128, 256, 0, stream>>>(lWi0, WTih0, 256, 128);
  k_transpose<<<64, 256, 0, stream>>>(lWh0, WThh0, 256, 64);
  k_transpose<<<64, 256, 0, stream>>>(lWi1, WTih1, 256, 64);
  k_transpose<<<64, 256, 0, stream>>>(lWh1, WThh1, 256, 64);
  k_transpose<<<64, 256, 0, stream>>>(lWi2, WTih2, 256, 64);
  k_transpose<<<64, 256, 0, stream>>>(lWh2, WThh2, 256, 64);
  hipMemcpyAsync(h, feats, (size_t)N_NODES * DIM * sizeof(float),
                 hipMemcpyDeviceToDevice, stream);

  for (int s = 0; s < NSTEPS; s++) {
    k_wh_mfma<<<N_NODES / 64, 256, 0, stream>>>(hb, WeTb, b_edge, Whb);
    k_scatter<<<NGRAPH, 512, 0, stream>>>(Whb, recs, rowsA, rowsB, ab);
    k_gru_mfma<<<N_NODES / 64, 256, 0, stream>>>(ab, hb, h, Wihb, Whhb, gbih, gbhh);
  }
  k_set2set<<<NGRAPH, 1024, 0, stream>>>(h, WTih0, WThh0, WTih1, WThh1, WTih2, WThh2,
                                         lbi0, lbh0, lbi1, lbh1, lbi2, lbh2, Wp, bp, out);
}

// Round 7
// 1573.801 us; speedup vs baseline: 2.5633x; 1.2149x over previous
//
#include <hip/hip_runtime.h>

typedef unsigned short u16;
typedef unsigned int u32;

#define N_NODES 64000
#define DIM 64
#define NGRAPH 320
#define NPG 200
#define NEDGE 1024000
#define EPG 3200
#define NSTEPS 5
#define NITERS 6

typedef __attribute__((ext_vector_type(8))) short bf16x8;
typedef __attribute__((ext_vector_type(4))) float f32x4;

__device__ __forceinline__ float bf2f(u16 u) {
  u32 x = ((u32)u) << 16;
  float f;
  __builtin_memcpy(&f, &x, 4);
  return f;
}
__device__ __forceinline__ u16 f2bf(float f) {
  u32 x;
  __builtin_memcpy(&x, &f, 4);
  x = (x + 0x7FFFu + ((x >> 16) & 1u)) >> 16;
  return (u16)x;
}
__device__ __forceinline__ float sigmf(float x) { return 1.0f / (1.0f + __expf(-x)); }

// ---------------- prep kernels ----------------

__global__ void __launch_bounds__(256) k_csr(const int* __restrict__ src,
                                             const int* __restrict__ dst,
                                             const int* __restrict__ ety,
                                             u16* __restrict__ recs,
                                             int* __restrict__ rowsA,
                                             int* __restrict__ rowsB) {
  __shared__ int cA[NPG], cB[NPG];
  __shared__ int rA[NPG + 1], rB[NPG + 1];
  int g = blockIdx.x, tid = threadIdx.x;
  int base = g * NPG;
  for (int i = tid; i < NPG; i += 256) { cA[i] = 0; cB[i] = 0; }
  __syncthreads();
  for (int e = tid; e < EPG; e += 256) {
    int d = dst[g * EPG + e] - base;
    int t = ety[g * EPG + e];
    atomicAdd(t < 3 ? &cA[d] : &cB[d], 1);
  }
  __syncthreads();
  if (tid == 0) {
    int s = 0;
    for (int n = 0; n < NPG; n++) { rA[n] = s; s += cA[n]; }
    rA[NPG] = s;
    for (int n = 0; n < NPG; n++) { rB[n] = s; s += cB[n]; }
    rB[NPG] = s;
  }
  __syncthreads();
  for (int i = tid; i < NPG; i += 256) { cA[i] = rA[i]; cB[i] = rB[i]; }
  __syncthreads();
  for (int e = tid; e < EPG; e += 256) {
    int d = dst[g * EPG + e] - base;
    int t = ety[g * EPG + e];
    int s = src[g * EPG + e] - base;
    int pos = atomicAdd(t < 3 ? &cA[d] : &cB[d], 1);
    recs[g * EPG + pos] = (u16)(s | ((t < 3 ? t : t - 3) << 8));
  }
  for (int i = tid; i <= NPG; i += 256) {
    rowsA[g * (NPG + 1) + i] = rA[i];
    rowsB[g * (NPG + 1) + i] = rB[i];
  }
}

__global__ void k_transpose(const float* __restrict__ src, float* __restrict__ dst, int R, int C) {
  int i = blockIdx.x * 256 + threadIdx.x;
  if (i < R * C) {
    int r = i / C, c = i - r * C;
    dst[c * R + r] = src[i];
  }
}

__global__ void k_cvt(const float* __restrict__ src, u16* __restrict__ dst, int n) {
  int i = blockIdx.x * 256 + threadIdx.x;
  if (i < n) dst[i] = f2bf(src[i]);
}

__global__ void k_cvt_weT(const float* __restrict__ W_edge, u16* __restrict__ WeT) {
  int i = blockIdx.x * 256 + threadIdx.x;
  if (i < 6 * 64 * 64) {
    int t = i >> 12, rem = i & 4095;
    int o = rem >> 6, k = rem & 63;
    WeT[i] = f2bf(W_edge[t * 4096 + k * 64 + o]);
  }
}

// ---------------- per-step kernels ----------------

__global__ void __launch_bounds__(256) k_wh_mfma(const u16* __restrict__ hb,
                                                 const u16* __restrict__ WeT,
                                                 const float* __restrict__ b_edge,
                                                 u16* __restrict__ Whb) {
  int tid = threadIdx.x;
  int lane = tid & 63, w = tid >> 6;
  int m = lane & 15, quad = lane >> 4;
  int nb = blockIdx.x * 64 + w * 16;
  const u16* ap = hb + (size_t)(nb + m) * 64 + quad * 8;
  bf16x8 a0 = *(const bf16x8*)ap;
  bf16x8 a1 = *(const bf16x8*)(ap + 32);
#pragma unroll
  for (int t = 0; t < 6; t++) {
#pragma unroll
    for (int ot = 0; ot < 4; ot++) {
      const u16* bp = WeT + ((t * 64 + ot * 16 + m) * 64) + quad * 8;
      bf16x8 b0 = *(const bf16x8*)bp;
      bf16x8 b1 = *(const bf16x8*)(bp + 32);
      f32x4 c = {0.f, 0.f, 0.f, 0.f};
      c = __builtin_amdgcn_mfma_f32_16x16x32_bf16(a0, b0, c, 0, 0, 0);
      c = __builtin_amdgcn_mfma_f32_16x16x32_bf16(a1, b1, c, 0, 0, 0);
      float bias = b_edge[t * 64 + ot * 16 + m];
#pragma unroll
      for (int r = 0; r < 4; r++) {
        int node = nb + quad * 4 + r;
        Whb[((size_t)t * N_NODES + node) * 64 + ot * 16 + m] = f2bf(c[r] + bias);
      }
    }
  }
}

__global__ void __launch_bounds__(512) k_scatter(const u16* __restrict__ Whb,
                                                 const u16* __restrict__ recs,
                                                 const int* __restrict__ rowsA,
                                                 const int* __restrict__ rowsB,
                                                 u16* __restrict__ ab) {
  __shared__ u16 wh_s[3 * NPG * 64];
  __shared__ u16 rec_s[EPG];
  __shared__ int rowA_s[NPG + 1];
  __shared__ int rowB_s[NPG + 1];
  int g = blockIdx.x;
  int tid = threadIdx.x, lane = tid & 63, wid = tid >> 6;
  size_t nodebase = (size_t)g * NPG;
  {
    const u32* r32 = (const u32*)(recs + g * EPG);
    u32* rs32 = (u32*)rec_s;
    for (int i = tid; i < EPG / 2; i += 512) rs32[i] = r32[i];
  }
  for (int i = tid; i <= NPG; i += 512) {
    rowA_s[i] = rowsA[g * (NPG + 1) + i];
    rowB_s[i] = rowsB[g * (NPG + 1) + i];
  }
  float acc_r[25];
#pragma unroll
  for (int q = 0; q < 25; q++) acc_r[q] = 0.f;
  for (int ph = 0; ph < 2; ph++) {
    __syncthreads();
    {
      u32* ws32 = (u32*)wh_s;
      for (int t = 0; t < 3; t++) {
        const u32* s32 = (const u32*)(Whb + ((size_t)(ph * 3 + t) * N_NODES + nodebase) * 64);
        for (int i = tid; i < NPG * 32; i += 512) ws32[t * NPG * 32 + i] = s32[i];
      }
    }
    __syncthreads();
    const int* row = ph ? rowB_s : rowA_s;
    for (int q = 0; q < 25; q++) {
      int n = q * 8 + wid;
      int rs = row[n], re = row[n + 1];
      float r = 0.f;
      int e = rs;
      for (; e + 4 <= re; e += 4) {
        int p0 = rec_s[e], p1 = rec_s[e + 1], p2 = rec_s[e + 2], p3 = rec_s[e + 3];
        float v0 = bf2f(wh_s[((p0 >> 8) * NPG + (p0 & 255)) * 64 + lane]);
        float v1 = bf2f(wh_s[((p1 >> 8) * NPG + (p1 & 255)) * 64 + lane]);
        float v2 = bf2f(wh_s[((p2 >> 8) * NPG + (p2 & 255)) * 64 + lane]);
        float v3 = bf2f(wh_s[((p3 >> 8) * NPG + (p3 & 255)) * 64 + lane]);
        r += v0 + v1 + v2 + v3;
      }
      for (; e < re; e++) {
        int p = rec_s[e];
        r += bf2f(wh_s[((p >> 8) * NPG + (p & 255)) * 64 + lane]);
      }
      acc_r[q] += r;
    }
  }
  u16* ag = ab + nodebase * 64;
#pragma unroll
  for (int q = 0; q < 25; q++) {
    int n = q * 8 + wid;
    ag[n * 64 + lane] = f2bf(acc_r[q]);
  }
}

__global__ void __launch_bounds__(256) k_gru_mfma(const u16* __restrict__ ab,
                                                  u16* __restrict__ hb,
                                                  float* __restrict__ h,
                                                  const u16* __restrict__ Wihb,
                                                  const u16* __restrict__ Whhb,
                                                  const float* __restrict__ b_ih,
                                                  const float* __restrict__ b_hh) {
  __shared__ float gsum[64 * 192];
  __shared__ float ghs[64 * 192];
  int tid = threadIdx.x;
  int lane = tid & 63, w = tid >> 6;
  int m = lane & 15, quad = lane >> 4;
  int nb = blockIdx.x * 64 + w * 16;
  const u16* aap = ab + (size_t)(nb + m) * 64 + quad * 8;
  const u16* ahp = hb + (size_t)(nb + m) * 64 + quad * 8;
  bf16x8 aa0 = *(const bf16x8*)aap;
  bf16x8 aa1 = *(const bf16x8*)(aap + 32);
  bf16x8 ah0 = *(const bf16x8*)ahp;
  bf16x8 ah1 = *(const bf16x8*)(ahp + 32);
#pragma unroll
  for (int jt = 0; jt < 12; jt++) {
    const u16* bip = Wihb + (jt * 16 + m) * 64 + quad * 8;
    const u16* bhp = Whhb + (jt * 16 + m) * 64 + quad * 8;
    bf16x8 bi0 = *(const bf16x8*)bip;
    bf16x8 bi1 = *(const bf16x8*)(bip + 32);
    bf16x8 bh0 = *(const bf16x8*)bhp;
    bf16x8 bh1 = *(const bf16x8*)(bhp + 32);
    f32x4 ci = {0.f, 0.f, 0.f, 0.f};
    ci = __builtin_amdgcn_mfma_f32_16x16x32_bf16(aa0, bi0, ci, 0, 0, 0);
    ci = __builtin_amdgcn_mfma_f32_16x16x32_bf16(aa1, bi1, ci, 0, 0, 0);
    f32x4 ch = {0.f, 0.f, 0.f, 0.f};
    ch = __builtin_amdgcn_mfma_f32_16x16x32_bf16(ah0, bh0, ch, 0, 0, 0);
    ch = __builtin_amdgcn_mfma_f32_16x16x32_bf16(ah1, bh1, ch, 0, 0, 0);
#pragma unroll
    for (int r = 0; r < 4; r++) {
      int n = w * 16 + quad * 4 + r;
      gsum[n * 192 + jt * 16 + m] = ci[r];
      ghs[n * 192 + jt * 16 + m] = ch[r];
    }
  }
  __syncthreads();
  int d = tid & 63, nl = tid >> 6;
  float bi_r = b_ih[d], bh_r = b_hh[d];
  float bi_z = b_ih[64 + d], bh_z = b_hh[64 + d];
  float bi_n = b_ih[128 + d], bh_n = b_hh[128 + d];
#pragma unroll
  for (int q = 0; q < 16; q++) {
    int n = q * 4 + nl;
    int base = n * 192 + d;
    float r = sigmf(gsum[base] + bi_r + ghs[base] + bh_r);
    float z = sigmf(gsum[base + 64] + bi_z + ghs[base + 64] + bh_z);
    float ng = tanhf(gsum[base + 128] + bi_n + r * (ghs[base + 128] + bh_n));
    size_t gidx = (size_t)(blockIdx.x * 64 + n) * 64 + d;
    float hv = h[gidx];
    float hn = (1.0f - z) * ng + z * hv;
    h[gidx] = hn;
    hb[gidx] = f2bf(hn);
  }
}

// ---------------- Set2Set v3: 512 threads, 2-way split-K, batched weight prefetch ----------------

__global__ void __launch_bounds__(512) k_set2set(
    const float* __restrict__ feat,
    const float* __restrict__ WTih0, const float* __restrict__ WThh0,
    const float* __restrict__ WTih1, const float* __restrict__ WThh1,
    const float* __restrict__ WTih2, const float* __restrict__ WThh2,
    const float* __restrict__ b_ih0, const float* __restrict__ b_hh0,
    const float* __restrict__ b_ih1, const float* __restrict__ b_hh1,
    const float* __restrict__ b_ih2, const float* __restrict__ b_hh2,
    const float* __restrict__ Wp, const float* __restrict__ bp,
    float* __restrict__ out) {
  __shared__ __align__(16) float feat_s[NPG * 64];
  __shared__ float qstar[128];
  __shared__ float xbuf[64];
  __shared__ float hs_s[3][64];
  __shared__ float cs_s[3][64];
  __shared__ float gates[256];
  __shared__ float gpart[2 * 256];
  __shared__ float e_s[NPG];
  __shared__ float red[8][64];
  __shared__ float scal[2];
  int tid = threadIdx.x;
  int g = blockIdx.x;
  int lane = tid & 63, wid = tid >> 6;
  int j = tid & 255, part = tid >> 8;  // wave-uniform part
  for (int i = tid; i < NPG * 64; i += 512) feat_s[i] = feat[(size_t)g * NPG * 64 + i];
  if (tid < 128) qstar[tid] = 0.f;
  if (tid < 64) {
    xbuf[tid] = 0.f;
    for (int l = 0; l < 3; l++) { hs_s[l][tid] = 0.f; cs_s[l][tid] = 0.f; }
  }
  __syncthreads();
  for (int it = 0; it < NITERS; it++) {
    // ---- LSTM layer 0: K=192 (qstar 128 | hs0 64); part0: k<96, part1: rest ----
    {
      float acc = 0.f;
      if (part == 0) {
        for (int k0 = 0; k0 < 96; k0 += 32) {
          float wv[32];
#pragma unroll
          for (int u = 0; u < 32; u++) wv[u] = WTih0[(k0 + u) * 256 + j];
#pragma unroll
          for (int u = 0; u < 32; u++) acc += qstar[k0 + u] * wv[u];
        }
      } else {
        {
          float wv[32];
#pragma unroll
          for (int u = 0; u < 32; u++) wv[u] = WTih0[(96 + u) * 256 + j];
#pragma unroll
          for (int u = 0; u < 32; u++) acc += qstar[96 + u] * wv[u];
        }
        for (int k0 = 0; k0 < 64; k0 += 32) {
          float wv[32];
#pragma unroll
          for (int u = 0; u < 32; u++) wv[u] = WThh0[(k0 + u) * 256 + j];
#pragma unroll
          for (int u = 0; u < 32; u++) acc += hs_s[0][k0 + u] * wv[u];
        }
      }
      gpart[part * 256 + j] = acc;
    }
    __syncthreads();
    if (tid < 256) gates[tid] = gpart[tid] + gpart[256 + tid] + b_ih0[tid] + b_hh0[tid];
    __syncthreads();
    if (tid < 64) {
      float c = sigmf(gates[64 + tid]) * cs_s[0][tid] + sigmf(gates[tid]) * tanhf(gates[128 + tid]);
      float x = sigmf(gates[192 + tid]) * tanhf(c);
      cs_s[0][tid] = c; hs_s[0][tid] = x; xbuf[tid] = x;
    }
    __syncthreads();
    // ---- LSTM layers 1,2: part0 sums xbuf@Wi, part1 sums hs@Wh (64 each) ----
    for (int l = 1; l < 3; l++) {
      const float* Wi = (l == 1) ? WTih1 : WTih2;
      const float* Wh = (l == 1) ? WThh1 : WThh2;
      const float* bi = (l == 1) ? b_ih1 : b_ih2;
      const float* bh = (l == 1) ? b_hh1 : b_hh2;
      const float* W = part ? Wh : Wi;
      const float* xv = part ? hs_s[l] : xbuf;
      float acc = 0.f;
      for (int k0 = 0; k0 < 64; k0 += 32) {
        float wv[32];
#pragma unroll
        for (int u = 0; u < 32; u++) wv[u] = W[(k0 + u) * 256 + j];
#pragma unroll
        for (int u = 0; u < 32; u++) acc += xv[k0 + u] * wv[u];
      }
      gpart[part * 256 + j] = acc;
      __syncthreads();
      if (tid < 256) gates[tid] = gpart[tid] + gpart[256 + tid] + bi[tid] + bh[tid];
      __syncthreads();
      if (tid < 64) {
        float c = sigmf(gates[64 + tid]) * cs_s[l][tid] + sigmf(gates[tid]) * tanhf(gates[128 + tid]);
        float x = sigmf(gates[192 + tid]) * tanhf(c);
        cs_s[l][tid] = c; hs_s[l][tid] = x; xbuf[tid] = x;
      }
      __syncthreads();
    }
    // ---- attention: 8 waves, 25 nodes each ----
    for (int n = wid; n < NPG; n += 8) {
      float v = feat_s[n * 64 + lane] * xbuf[lane];
      for (int off = 32; off > 0; off >>= 1) v += __shfl_down(v, off);
      if (lane == 0) e_s[n] = v;
    }
    __syncthreads();
    if (tid < 64) {
      float mx = -1e30f;
      for (int n = lane; n < NPG; n += 64) mx = fmaxf(mx, e_s[n]);
      for (int off = 32; off > 0; off >>= 1) mx = fmaxf(mx, __shfl_down(mx, off));
      mx = __shfl(mx, 0);
      float ssum = 0.f;
      for (int n = lane; n < NPG; n += 64) {
        float ex = __expf(e_s[n] - mx);
        e_s[n] = ex;
        ssum += ex;
      }
      for (int off = 32; off > 0; off >>= 1) ssum += __shfl_down(ssum, off);
      if (lane == 0) scal[0] = ssum;
    }
    __syncthreads();
    float denom = scal[0];
    {
      float r = 0.f;
      for (int n = wid; n < NPG; n += 8) r += feat_s[n * 64 + lane] * e_s[n];
      red[wid][lane] = r;
    }
    __syncthreads();
    if (tid < 64) {
      float ro = 0.f;
#pragma unroll
      for (int ww = 0; ww < 8; ww++) ro += red[ww][lane];
      qstar[lane] = xbuf[lane];
      qstar[64 + lane] = ro / denom;
    }
    __syncthreads();
  }
  if (tid < 3) {
    float s = bp[tid];
    for (int k = 0; k < 128; k++) s += qstar[k] * Wp[tid * 128 + k];
    out[g * 3 + tid] = s;
  }
}

// ---------------- host ----------------

extern "C" void kernel_launch(void* const* d_in, const int* in_sizes, int n_in,
                              void* d_out, int out_size, void* d_ws, size_t ws_size,
                              hipStream_t stream) {
  const float* feats  = (const float*)d_in[0];
  const float* W_edge = (const float*)d_in[1];
  const float* b_edge = (const float*)d_in[2];
  const float* gWih   = (const float*)d_in[3];
  const float* gWhh   = (const float*)d_in[4];
  const float* gbih   = (const float*)d_in[5];
  const float* gbhh   = (const float*)d_in[6];
  const float* lWi0   = (const float*)d_in[7];
  const float* lWh0   = (const float*)d_in[8];
  const float* lbi0   = (const float*)d_in[9];
  const float* lbh0   = (const float*)d_in[10];
  const float* lWi1   = (const float*)d_in[11];
  const float* lWh1   = (const float*)d_in[12];
  const float* lbi1   = (const float*)d_in[13];
  const float* lbh1   = (const float*)d_in[14];
  const float* lWi2   = (const float*)d_in[15];
  const float* lWh2   = (const float*)d_in[16];
  const float* lbi2   = (const float*)d_in[17];
  const float* lbh2   = (const float*)d_in[18];
  const float* Wp     = (const float*)d_in[19];
  const float* bp     = (const float*)d_in[20];
  const int* src      = (const int*)d_in[21];
  const int* dst      = (const int*)d_in[22];
  const int* ety      = (const int*)d_in[23];
  float* out = (float*)d_out;

  char* ws = (char*)d_ws;
  float* h      = (float*)ws;                    // 16,384,000 B
  u16*   hb     = (u16*)(ws + 16384000);         //  8,192,000 B
  u16*   ab     = (u16*)(ws + 24576000);         //  8,192,000 B
  u16*   Whb    = (u16*)(ws + 32768000);         // 49,152,000 B
  u16*   recs   = (u16*)(ws + 81920000);         //  2,048,000 B
  int*   rowsA  = (int*)(ws + 83968000);         //    257,280 B
  int*   rowsB  = (int*)(ws + 84225280);         //    257,280 B
  u16*   WeTb   = (u16*)(ws + 84482560);         //     49,152 B
  u16*   Wihb   = (u16*)(ws + 84531712);         //     24,576 B
  u16*   Whhb   = (u16*)(ws + 84556288);         //     24,576 B
  float* wtl    = (float*)(ws + 84580864);       //    458,752 B
  float* WTih0 = wtl;
  float* WThh0 = WTih0 + 32768;
  float* WTih1 = WThh0 + 16384;
  float* WThh1 = WTih1 + 16384;
  float* WTih2 = WThh1 + 16384;
  float* WThh2 = WTih2 + 16384;

  k_csr<<<NGRAPH, 256, 0, stream>>>(src, dst, ety, recs, rowsA, rowsB);
  k_cvt<<<(N_NODES * DIM + 255) / 256, 256, 0, stream>>>(feats, hb, N_NODES * DIM);
  k_cvt<<<48, 256, 0, stream>>>(gWih, Wihb, 12288);
  k_cvt<<<48, 256, 0, stream>>>(gWhh, Whhb, 12288);
  k_cvt_weT<<<96, 256, 0, stream>>>(W_edge, WeTb);
  k_transpose<<<128, 256, 0, stream>>>(lWi0, WTih0, 256, 128);
  k_transpose<<<64, 256, 0, stream>>>(lWh0, WThh0, 256, 64);
  k_transpose<<<64, 256, 0, stream>>>(lWi1, WTih1, 256, 64);
  k_transpose<<<64, 256, 0, stream>>>(lWh1, WThh1, 256, 64);
  k_transpose<<<64, 256, 0, stream>>>(lWi2, WTih2, 256, 64);
  k_transpose<<<64, 256, 0, stream>>>(lWh2, WThh2, 256, 64);
  hipMemcpyAsync(h, feats, (size_t)N_NODES * DIM * sizeof(float),
                 hipMemcpyDeviceToDevice, stream);

  for (int s = 0; s < NSTEPS; s++) {
    k_wh_mfma<<<N_NODES / 64, 256, 0, stream>>>(hb, WeTb, b_edge, Whb);
    k_scatter<<<NGRAPH, 512, 0, stream>>>(Whb, recs, rowsA, rowsB, ab);
    k_gru_mfma<<<N_NODES / 64, 256, 0, stream>>>(ab, hb, h, Wihb, Whhb, gbih, gbhh);
  }
  k_set2set<<<NGRAPH, 512, 0, stream>>>(h, WTih0, WThh0, WTih1, WThh1, WTih2, WThh2,
                                        lbi0, lbh0, lbi1, lbh1, lbi2, lbh2, Wp, bp, out);
}

// Round 8
// 1135.215 us; speedup vs baseline: 3.5536x; 1.3863x over previous
//
#include <hip/hip_runtime.h>

typedef unsigned short u16;
typedef unsigned int u32;

#define N_NODES 64000
#define DIM 64
#define NGRAPH 320
#define NPG 200
#define NEDGE 1024000
#define EPG 3200
#define NSTEPS 5
#define NITERS 6

typedef __attribute__((ext_vector_type(8))) short bf16x8;
typedef __attribute__((ext_vector_type(4))) float f32x4;

__device__ __forceinline__ float bf2f(u16 u) {
  u32 x = ((u32)u) << 16;
  float f;
  __builtin_memcpy(&f, &x, 4);
  return f;
}
__device__ __forceinline__ u16 f2bf(float f) {
  u32 x;
  __builtin_memcpy(&x, &f, 4);
  x = (x + 0x7FFFu + ((x >> 16) & 1u)) >> 16;
  return (u16)x;
}
__device__ __forceinline__ float sigmf(float x) { return 1.0f / (1.0f + __expf(-x)); }

// ---------------- prep kernels ----------------

__global__ void __launch_bounds__(256) k_csr(const int* __restrict__ src,
                                             const int* __restrict__ dst,
                                             const int* __restrict__ ety,
                                             u16* __restrict__ recs,
                                             int* __restrict__ rowsA,
                                             int* __restrict__ rowsB) {
  __shared__ int cA[NPG], cB[NPG];
  __shared__ int rA[NPG + 1], rB[NPG + 1];
  int g = blockIdx.x, tid = threadIdx.x;
  int base = g * NPG;
  for (int i = tid; i < NPG; i += 256) { cA[i] = 0; cB[i] = 0; }
  __syncthreads();
  for (int e = tid; e < EPG; e += 256) {
    int d = dst[g * EPG + e] - base;
    int t = ety[g * EPG + e];
    atomicAdd(t < 3 ? &cA[d] : &cB[d], 1);
  }
  __syncthreads();
  if (tid == 0) {
    int s = 0;
    for (int n = 0; n < NPG; n++) { rA[n] = s; s += cA[n]; }
    rA[NPG] = s;
    for (int n = 0; n < NPG; n++) { rB[n] = s; s += cB[n]; }
    rB[NPG] = s;
  }
  __syncthreads();
  for (int i = tid; i < NPG; i += 256) { cA[i] = rA[i]; cB[i] = rB[i]; }
  __syncthreads();
  for (int e = tid; e < EPG; e += 256) {
    int d = dst[g * EPG + e] - base;
    int t = ety[g * EPG + e];
    int s = src[g * EPG + e] - base;
    int pos = atomicAdd(t < 3 ? &cA[d] : &cB[d], 1);
    recs[g * EPG + pos] = (u16)(s | ((t < 3 ? t : t - 3) << 8));
  }
  for (int i = tid; i <= NPG; i += 256) {
    rowsA[g * (NPG + 1) + i] = rA[i];
    rowsB[g * (NPG + 1) + i] = rB[i];
  }
}

__global__ void k_transpose(const float* __restrict__ src, float* __restrict__ dst, int R, int C) {
  int i = blockIdx.x * 256 + threadIdx.x;
  if (i < R * C) {
    int r = i / C, c = i - r * C;
    dst[c * R + r] = src[i];
  }
}

__global__ void k_cvt(const float* __restrict__ src, u16* __restrict__ dst, int n) {
  int i = blockIdx.x * 256 + threadIdx.x;
  if (i < n) dst[i] = f2bf(src[i]);
}

__global__ void k_cvt_weT(const float* __restrict__ W_edge, u16* __restrict__ WeT) {
  int i = blockIdx.x * 256 + threadIdx.x;
  if (i < 6 * 64 * 64) {
    int t = i >> 12, rem = i & 4095;
    int o = rem >> 6, k = rem & 63;
    WeT[i] = f2bf(W_edge[t * 4096 + k * 64 + o]);
  }
}

// ---------------- per-step kernels ----------------

__global__ void __launch_bounds__(256) k_wh_mfma(const u16* __restrict__ hb,
                                                 const u16* __restrict__ WeT,
                                                 const float* __restrict__ b_edge,
                                                 u16* __restrict__ Whb) {
  int tid = threadIdx.x;
  int lane = tid & 63, w = tid >> 6;
  int m = lane & 15, quad = lane >> 4;
  int nb = blockIdx.x * 64 + w * 16;
  const u16* ap = hb + (size_t)(nb + m) * 64 + quad * 8;
  bf16x8 a0 = *(const bf16x8*)ap;
  bf16x8 a1 = *(const bf16x8*)(ap + 32);
#pragma unroll
  for (int t = 0; t < 6; t++) {
#pragma unroll
    for (int ot = 0; ot < 4; ot++) {
      const u16* bp = WeT + ((t * 64 + ot * 16 + m) * 64) + quad * 8;
      bf16x8 b0 = *(const bf16x8*)bp;
      bf16x8 b1 = *(const bf16x8*)(bp + 32);
      f32x4 c = {0.f, 0.f, 0.f, 0.f};
      c = __builtin_amdgcn_mfma_f32_16x16x32_bf16(a0, b0, c, 0, 0, 0);
      c = __builtin_amdgcn_mfma_f32_16x16x32_bf16(a1, b1, c, 0, 0, 0);
      float bias = b_edge[t * 64 + ot * 16 + m];
#pragma unroll
      for (int r = 0; r < 4; r++) {
        int node = nb + quad * 4 + r;
        Whb[((size_t)t * N_NODES + node) * 64 + ot * 16 + m] = f2bf(c[r] + bias);
      }
    }
  }
}

__global__ void __launch_bounds__(512) k_scatter(const u16* __restrict__ Whb,
                                                 const u16* __restrict__ recs,
                                                 const int* __restrict__ rowsA,
                                                 const int* __restrict__ rowsB,
                                                 u16* __restrict__ ab) {
  __shared__ u16 wh_s[3 * NPG * 64];
  __shared__ u16 rec_s[EPG];
  __shared__ int rowA_s[NPG + 1];
  __shared__ int rowB_s[NPG + 1];
  int g = blockIdx.x;
  int tid = threadIdx.x, lane = tid & 63, wid = tid >> 6;
  size_t nodebase = (size_t)g * NPG;
  {
    const u32* r32 = (const u32*)(recs + g * EPG);
    u32* rs32 = (u32*)rec_s;
    for (int i = tid; i < EPG / 2; i += 512) rs32[i] = r32[i];
  }
  for (int i = tid; i <= NPG; i += 512) {
    rowA_s[i] = rowsA[g * (NPG + 1) + i];
    rowB_s[i] = rowsB[g * (NPG + 1) + i];
  }
  float acc_r[25];
#pragma unroll
  for (int q = 0; q < 25; q++) acc_r[q] = 0.f;
  for (int ph = 0; ph < 2; ph++) {
    __syncthreads();
    {
      u32* ws32 = (u32*)wh_s;
      for (int t = 0; t < 3; t++) {
        const u32* s32 = (const u32*)(Whb + ((size_t)(ph * 3 + t) * N_NODES + nodebase) * 64);
        for (int i = tid; i < NPG * 32; i += 512) ws32[t * NPG * 32 + i] = s32[i];
      }
    }
    __syncthreads();
    const int* row = ph ? rowB_s : rowA_s;
    for (int q = 0; q < 25; q++) {
      int n = q * 8 + wid;
      int rs = row[n], re = row[n + 1];
      float r = 0.f;
      int e = rs;
      for (; e + 4 <= re; e += 4) {
        int p0 = rec_s[e], p1 = rec_s[e + 1], p2 = rec_s[e + 2], p3 = rec_s[e + 3];
        float v0 = bf2f(wh_s[((p0 >> 8) * NPG + (p0 & 255)) * 64 + lane]);
        float v1 = bf2f(wh_s[((p1 >> 8) * NPG + (p1 & 255)) * 64 + lane]);
        float v2 = bf2f(wh_s[((p2 >> 8) * NPG + (p2 & 255)) * 64 + lane]);
        float v3 = bf2f(wh_s[((p3 >> 8) * NPG + (p3 & 255)) * 64 + lane]);
        r += v0 + v1 + v2 + v3;
      }
      for (; e < re; e++) {
        int p = rec_s[e];
        r += bf2f(wh_s[((p >> 8) * NPG + (p & 255)) * 64 + lane]);
      }
      acc_r[q] += r;
    }
  }
  u16* ag = ab + nodebase * 64;
#pragma unroll
  for (int q = 0; q < 25; q++) {
    int n = q * 8 + wid;
    ag[n * 64 + lane] = f2bf(acc_r[q]);
  }
}

// GRU v2: all 24 accumulators in registers; gate epilogue from registers
// (C-layout: col=lane&15 -> gate j = jt*16+col, row=quad*4+r -> node).
// Only hn staged through padded LDS for coalesced stores. LDS 17.4KB.
__global__ void __launch_bounds__(256) k_gru_mfma(const u16* __restrict__ ab,
                                                  u16* __restrict__ hb,
                                                  float* __restrict__ h,
                                                  const u16* __restrict__ Wihb,
                                                  const u16* __restrict__ Whhb,
                                                  const float* __restrict__ b_ih,
                                                  const float* __restrict__ b_hh) {
  __shared__ float hn_s[64 * 68];
  int tid = threadIdx.x;
  int lane = tid & 63, w = tid >> 6;
  int c = lane & 15, quad = lane >> 4;
  int nb = blockIdx.x * 64 + w * 16;
  const u16* aap = ab + (size_t)(nb + c) * 64 + quad * 8;
  const u16* ahp = hb + (size_t)(nb + c) * 64 + quad * 8;
  bf16x8 aa0 = *(const bf16x8*)aap;
  bf16x8 aa1 = *(const bf16x8*)(aap + 32);
  bf16x8 ah0 = *(const bf16x8*)ahp;
  bf16x8 ah1 = *(const bf16x8*)(ahp + 32);
  f32x4 ci[12], ch[12];
#pragma unroll
  for (int jt = 0; jt < 12; jt++) {
    const u16* bip = Wihb + (jt * 16 + c) * 64 + quad * 8;
    const u16* bhp = Whhb + (jt * 16 + c) * 64 + quad * 8;
    bf16x8 bi0 = *(const bf16x8*)bip;
    bf16x8 bi1 = *(const bf16x8*)(bip + 32);
    bf16x8 bh0 = *(const bf16x8*)bhp;
    bf16x8 bh1 = *(const bf16x8*)(bhp + 32);
    f32x4 z4 = {0.f, 0.f, 0.f, 0.f};
    ci[jt] = __builtin_amdgcn_mfma_f32_16x16x32_bf16(aa0, bi0, z4, 0, 0, 0);
    ci[jt] = __builtin_amdgcn_mfma_f32_16x16x32_bf16(aa1, bi1, ci[jt], 0, 0, 0);
    ch[jt] = __builtin_amdgcn_mfma_f32_16x16x32_bf16(ah0, bh0, z4, 0, 0, 0);
    ch[jt] = __builtin_amdgcn_mfma_f32_16x16x32_bf16(ah1, bh1, ch[jt], 0, 0, 0);
  }
  float bir[4], bhr[4], biz[4], bhz[4], bin_[4], bhn[4];
#pragma unroll
  for (int dq = 0; dq < 4; dq++) {
    int d = dq * 16 + c;
    bir[dq] = b_ih[d];        bhr[dq] = b_hh[d];
    biz[dq] = b_ih[64 + d];   bhz[dq] = b_hh[64 + d];
    bin_[dq] = b_ih[128 + d]; bhn[dq] = b_hh[128 + d];
  }
#pragma unroll
  for (int r = 0; r < 4; r++) {
    int node = nb + quad * 4 + r;
    int nl = w * 16 + quad * 4 + r;
#pragma unroll
    for (int dq = 0; dq < 4; dq++) {
      int d = dq * 16 + c;
      float rr = sigmf(ci[dq][r] + ch[dq][r] + bir[dq] + bhr[dq]);
      float zz = sigmf(ci[4 + dq][r] + ch[4 + dq][r] + biz[dq] + bhz[dq]);
      float nn = tanhf(ci[8 + dq][r] + bin_[dq] + rr * (ch[8 + dq][r] + bhn[dq]));
      float hv = h[(size_t)node * 64 + d];
      hn_s[nl * 68 + d] = (1.0f - zz) * nn + zz * hv;
    }
  }
  __syncthreads();
  for (int i = tid; i < 4096; i += 256) {
    int n = i >> 6, d = i & 63;
    float v = hn_s[n * 68 + d];
    size_t gidx = (size_t)blockIdx.x * 4096 + i;
    h[gidx] = v;
    hb[gidx] = f2bf(v);
  }
}

// ---------------- Set2Set v4: 512 thr, (512,1) bounds, bf16 weights, plain loops ----------------

__global__ void __launch_bounds__(512, 1) k_set2set(
    const float* __restrict__ feat,
    const u16* __restrict__ WTih0b, const u16* __restrict__ WThh0b,
    const u16* __restrict__ WTih1b, const u16* __restrict__ WThh1b,
    const u16* __restrict__ WTih2b, const u16* __restrict__ WThh2b,
    const float* __restrict__ b_ih0, const float* __restrict__ b_hh0,
    const float* __restrict__ b_ih1, const float* __restrict__ b_hh1,
    const float* __restrict__ b_ih2, const float* __restrict__ b_hh2,
    const float* __restrict__ Wp, const float* __restrict__ bp,
    float* __restrict__ out) {
  __shared__ __align__(16) float feat_s[NPG * 64];
  __shared__ float qstar[128];
  __shared__ float xbuf[64];
  __shared__ float hs_s[3][64];
  __shared__ float cs_s[3][64];
  __shared__ float gates[256];
  __shared__ float gpart[2 * 256];
  __shared__ float e_s[NPG];
  __shared__ float red[8][64];
  __shared__ float scal[2];
  int tid = threadIdx.x;
  int g = blockIdx.x;
  int lane = tid & 63, wid = tid >> 6;
  int j = tid & 255, part = tid >> 8;  // wave-uniform part
  for (int i = tid; i < NPG * 64; i += 512) feat_s[i] = feat[(size_t)g * NPG * 64 + i];
  if (tid < 128) qstar[tid] = 0.f;
  if (tid < 64) {
    xbuf[tid] = 0.f;
    for (int l = 0; l < 3; l++) { hs_s[l][tid] = 0.f; cs_s[l][tid] = 0.f; }
  }
  __syncthreads();
  for (int it = 0; it < NITERS; it++) {
    // ---- layer 0: K=192 (qstar 128 | hs0 64); part0: k<96, part1: rest ----
    {
      float acc = 0.f;
      if (part == 0) {
#pragma unroll 8
        for (int k = 0; k < 96; k++) acc += qstar[k] * bf2f(WTih0b[k * 256 + j]);
      } else {
#pragma unroll 8
        for (int k = 96; k < 128; k++) acc += qstar[k] * bf2f(WTih0b[k * 256 + j]);
#pragma unroll 8
        for (int k = 0; k < 64; k++) acc += hs_s[0][k] * bf2f(WThh0b[k * 256 + j]);
      }
      gpart[part * 256 + j] = acc;
    }
    __syncthreads();
    if (tid < 256) gates[tid] = gpart[tid] + gpart[256 + tid] + b_ih0[tid] + b_hh0[tid];
    __syncthreads();
    if (tid < 64) {
      float c = sigmf(gates[64 + tid]) * cs_s[0][tid] + sigmf(gates[tid]) * tanhf(gates[128 + tid]);
      float x = sigmf(gates[192 + tid]) * tanhf(c);
      cs_s[0][tid] = c; hs_s[0][tid] = x; xbuf[tid] = x;
    }
    __syncthreads();
    // ---- layers 1,2: part0 xbuf@Wi, part1 hs@Wh (K=64 each) ----
    for (int l = 1; l < 3; l++) {
      const u16* Wi = (l == 1) ? WTih1b : WTih2b;
      const u16* Wh = (l == 1) ? WThh1b : WThh2b;
      const float* bi = (l == 1) ? b_ih1 : b_ih2;
      const float* bh = (l == 1) ? b_hh1 : b_hh2;
      const u16* W = part ? Wh : Wi;
      const float* xv = part ? hs_s[l] : xbuf;
      float acc = 0.f;
#pragma unroll 8
      for (int k = 0; k < 64; k++) acc += xv[k] * bf2f(W[k * 256 + j]);
      gpart[part * 256 + j] = acc;
      __syncthreads();
      if (tid < 256) gates[tid] = gpart[tid] + gpart[256 + tid] + bi[tid] + bh[tid];
      __syncthreads();
      if (tid < 64) {
        float c = sigmf(gates[64 + tid]) * cs_s[l][tid] + sigmf(gates[tid]) * tanhf(gates[128 + tid]);
        float x = sigmf(gates[192 + tid]) * tanhf(c);
        cs_s[l][tid] = c; hs_s[l][tid] = x; xbuf[tid] = x;
      }
      __syncthreads();
    }
    // ---- attention: 8 waves, 25 nodes each ----
    for (int n = wid; n < NPG; n += 8) {
      float v = feat_s[n * 64 + lane] * xbuf[lane];
      for (int off = 32; off > 0; off >>= 1) v += __shfl_down(v, off);
      if (lane == 0) e_s[n] = v;
    }
    __syncthreads();
    if (tid < 64) {
      float mx = -1e30f;
      for (int n = lane; n < NPG; n += 64) mx = fmaxf(mx, e_s[n]);
      for (int off = 32; off > 0; off >>= 1) mx = fmaxf(mx, __shfl_down(mx, off));
      mx = __shfl(mx, 0);
      float ssum = 0.f;
      for (int n = lane; n < NPG; n += 64) {
        float ex = __expf(e_s[n] - mx);
        e_s[n] = ex;
        ssum += ex;
      }
      for (int off = 32; off > 0; off >>= 1) ssum += __shfl_down(ssum, off);
      if (lane == 0) scal[0] = ssum;
    }
    __syncthreads();
    float denom = scal[0];
    {
      float r = 0.f;
      for (int n = wid; n < NPG; n += 8) r += feat_s[n * 64 + lane] * e_s[n];
      red[wid][lane] = r;
    }
    __syncthreads();
    if (tid < 64) {
      float ro = 0.f;
#pragma unroll
      for (int ww = 0; ww < 8; ww++) ro += red[ww][lane];
      qstar[lane] = xbuf[lane];
      qstar[64 + lane] = ro / denom;
    }
    __syncthreads();
  }
  if (tid < 3) {
    float s = bp[tid];
    for (int k = 0; k < 128; k++) s += qstar[k] * Wp[tid * 128 + k];
    out[g * 3 + tid] = s;
  }
}

// ---------------- host ----------------

extern "C" void kernel_launch(void* const* d_in, const int* in_sizes, int n_in,
                              void* d_out, int out_size, void* d_ws, size_t ws_size,
                              hipStream_t stream) {
  const float* feats  = (const float*)d_in[0];
  const float* W_edge = (const float*)d_in[1];
  const float* b_edge = (const float*)d_in[2];
  const float* gWih   = (const float*)d_in[3];
  const float* gWhh   = (const float*)d_in[4];
  const float* gbih   = (const float*)d_in[5];
  const float* gbhh   = (const float*)d_in[6];
  const float* lWi0   = (const float*)d_in[7];
  const float* lWh0   = (const float*)d_in[8];
  const float* lbi0   = (const float*)d_in[9];
  const float* lbh0   = (const float*)d_in[10];
  const float* lWi1   = (const float*)d_in[11];
  const float* lWh1   = (const float*)d_in[12];
  const float* lbi1   = (const float*)d_in[13];
  const float* lbh1   = (const float*)d_in[14];
  const float* lWi2   = (const float*)d_in[15];
  const float* lWh2   = (const float*)d_in[16];
  const float* lbi2   = (const float*)d_in[17];
  const float* lbh2   = (const float*)d_in[18];
  const float* Wp     = (const float*)d_in[19];
  const float* bp     = (const float*)d_in[20];
  const int* src      = (const int*)d_in[21];
  const int* dst      = (const int*)d_in[22];
  const int* ety      = (const int*)d_in[23];
  float* out = (float*)d_out;

  char* ws = (char*)d_ws;
  float* h      = (float*)ws;                    // 16,384,000 B
  u16*   hb     = (u16*)(ws + 16384000);         //  8,192,000 B
  u16*   ab     = (u16*)(ws + 24576000);         //  8,192,000 B
  u16*   Whb    = (u16*)(ws + 32768000);         // 49,152,000 B
  u16*   recs   = (u16*)(ws + 81920000);         //  2,048,000 B
  int*   rowsA  = (int*)(ws + 83968000);         //    257,280 B
  int*   rowsB  = (int*)(ws + 84225280);         //    257,280 B
  u16*   WeTb   = (u16*)(ws + 84482560);         //     49,152 B
  u16*   Wihb   = (u16*)(ws + 84531712);         //     24,576 B
  u16*   Whhb   = (u16*)(ws + 84556288);         //     24,576 B
  float* wtl    = (float*)(ws + 84580864);       //    458,752 B
  float* WTih0 = wtl;
  float* WThh0 = WTih0 + 32768;
  float* WTih1 = WThh0 + 16384;
  float* WThh1 = WTih1 + 16384;
  float* WTih2 = WThh1 + 16384;
  float* WThh2 = WTih2 + 16384;
  u16* lstmb = (u16*)(ws + 85039616);            //    229,376 B
  u16* WTih0b = lstmb;
  u16* WThh0b = WTih0b + 32768;
  u16* WTih1b = WThh0b + 16384;
  u16* WThh1b = WTih1b + 16384;
  u16* WTih2b = WThh1b + 16384;
  u16* WThh2b = WTih2b + 16384;

  k_csr<<<NGRAPH, 256, 0, stream>>>(src, dst, ety, recs, rowsA, rowsB);
  k_cvt<<<(N_NODES * DIM + 255) / 256, 256, 0, stream>>>(feats, hb, N_NODES * DIM);
  k_cvt<<<48, 256, 0, stream>>>(gWih, Wihb, 12288);
  k_cvt<<<48, 256, 0, stream>>>(gWhh, Whhb, 12288);
  k_cvt_weT<<<96, 256, 0, stream>>>(W_edge, WeTb);
  k_transpose<<<128, 256, 0, stream>>>(lWi0, WTih0, 256, 128);
  k_transpose<<<64, 256, 0, stream>>>(lWh0, WThh0, 256, 64);
  k_transpose<<<64, 256, 0, stream>>>(lWi1, WTih1, 256, 64);
  k_transpose<<<64, 256, 0, stream>>>(lWh1, WThh1, 256, 64);
  k_transpose<<<64, 256, 0, stream>>>(lWi2, WTih2, 256, 64);
  k_transpose<<<64, 256, 0, stream>>>(lWh2, WThh2, 256, 64);
  k_cvt<<<128, 256, 0, stream>>>(WTih0, WTih0b, 32768);
  k_cvt<<<64, 256, 0, stream>>>(WThh0, WThh0b, 16384);
  k_cvt<<<64, 256, 0, stream>>>(WTih1, WTih1b, 16384);
  k_cvt<<<64, 256, 0, stream>>>(WThh1, WThh1b, 16384);
  k_cvt<<<64, 256, 0, stream>>>(WTih2, WTih2b, 16384);
  k_cvt<<<64, 256, 0, stream>>>(WThh2, WThh2b, 16384);
  hipMemcpyAsync(h, feats, (size_t)N_NODES * DIM * sizeof(float),
                 hipMemcpyDeviceToDevice, stream);

  for (int s = 0; s < NSTEPS; s++) {
    k_wh_mfma<<<N_NODES / 64, 256, 0, stream>>>(hb, WeTb, b_edge, Whb);
    k_scatter<<<NGRAPH, 512, 0, stream>>>(Whb, recs, rowsA, rowsB, ab);
    k_gru_mfma<<<N_NODES / 64, 256, 0, stream>>>(ab, hb, h, Wihb, Whhb, gbih, gbhh);
  }
  k_set2set<<<NGRAPH, 512, 0, stream>>>(h, WTih0b, WThh0b, WTih1b, WThh1b, WTih2b, WThh2b,
                                        lbi0, lbh0, lbi1, lbh1, lbi2, lbh2, Wp, bp, out);
}